// Round 1
// baseline (294.694 us; speedup 1.0000x reference)
//
#include <hip/hip_runtime.h>
#include <hip/hip_bf16.h>
#include <stdint.h>

typedef __bf16 bf16;
typedef __bf16 bf16x8 __attribute__((ext_vector_type(8)));
typedef __bf16 bf16x4 __attribute__((ext_vector_type(4)));
typedef float f32x4 __attribute__((ext_vector_type(4)));

#define B_  2
#define S_  2048
#define D_  1024
#define H_  16
#define HD_ 64

typedef __attribute__((address_space(1))) uint32_t gu32;
typedef __attribute__((address_space(3))) uint32_t lu32;

// async global->LDS, 16B per lane. lds must be wave-uniform; g is per-lane.
__device__ __forceinline__ void gload16(void* lds, const void* g) {
  __builtin_amdgcn_global_load_lds((const gu32*)(uintptr_t)g,
                                   (lu32*)(uint32_t)(uintptr_t)lds,
                                   16, 0, 0);
}

// ---------------------------------------------------------------- cast x
__global__ __launch_bounds__(256) void cast_f32_bf16(
    const float* __restrict__ in, bf16* __restrict__ out, int n4) {
  int i = blockIdx.x * 256 + threadIdx.x;
  if (i < n4) {
    float4 v = ((const float4*)in)[i];
    bf16x4 o = {(bf16)v.x, (bf16)v.y, (bf16)v.z, (bf16)v.w};
    ((bf16x4*)out)[i] = o;
  }
}

// ------------------------------------------------- transpose-cast weights
// out[z] is [N][K] bf16 with out[z][n][k] = W_z[k][n]
__global__ __launch_bounds__(256) void wtrans(
    const float* __restrict__ w0, const float* __restrict__ w1,
    const float* __restrict__ w2, const float* __restrict__ w3,
    bf16* __restrict__ out) {
  int z = blockIdx.z;
  const float* src = (z == 0) ? w0 : (z == 1) ? w1 : (z == 2) ? w2 : w3;
  bf16* dst = out + ((size_t)z << 20);
  __shared__ float tile[32][33];
  int tx = threadIdx.x, ty = threadIdx.y;
  int x0 = blockIdx.x * 32, y0 = blockIdx.y * 32;
#pragma unroll
  for (int r = 0; r < 4; ++r)
    tile[ty + r * 8][tx] = src[(size_t)(y0 + ty + r * 8) * D_ + x0 + tx];
  __syncthreads();
#pragma unroll
  for (int r = 0; r < 4; ++r)
    dst[(size_t)(x0 + ty + r * 8) * D_ + y0 + tx] = (bf16)tile[tx][ty + r * 8];
}

// ---------------------------------------------------------------- GEMM
// C[m][n] = sum_k A[m][k] * Bt[n][k] + bias[n]
// mode 0: outb[m*N+n] bf16 ; mode 1: V^T scatter outb[((b*H+h)*HD+d)*S+s]
// mode 2: outf[m*N+n] f32
__global__ __launch_bounds__(256) void gemm128(
    const bf16* __restrict__ A, const bf16* __restrict__ Bt,
    const float* __restrict__ bias,
    bf16* __restrict__ outb, float* __restrict__ outf,
    int M, int N, int K, int mode) {
  __shared__ bf16 As[128 * 64];
  __shared__ bf16 Bs[128 * 64];
  int tid = threadIdx.x;
  int lane = tid & 63, wid = tid >> 6;
  int ln15 = lane & 15, lg = lane >> 4;
  int wr = wid >> 1, wc = wid & 1;
  int m0 = blockIdx.y * 128, n0 = blockIdx.x * 128;

  f32x4 acc[4][4] = {};

  for (int k0 = 0; k0 < K; k0 += 64) {
#pragma unroll
    for (int i = 0; i < 4; ++i) {
      int idx = (i * 256 + tid) * 8;
      int r = idx >> 6, c = idx & 63;
      gload16(&As[(size_t)(i * 256 + wid * 64) * 8],
              A + (size_t)(m0 + r) * K + k0 + c);
      gload16(&Bs[(size_t)(i * 256 + wid * 64) * 8],
              Bt + (size_t)(n0 + r) * K + k0 + c);
    }
    __syncthreads();
#pragma unroll
    for (int kk = 0; kk < 64; kk += 32) {
      bf16x8 af[4], bf[4];
#pragma unroll
      for (int t = 0; t < 4; ++t)
        af[t] = *(const bf16x8*)&As[(wr * 64 + t * 16 + ln15) * 64 + kk + lg * 8];
#pragma unroll
      for (int t = 0; t < 4; ++t)
        bf[t] = *(const bf16x8*)&Bs[(wc * 64 + t * 16 + ln15) * 64 + kk + lg * 8];
#pragma unroll
      for (int mi = 0; mi < 4; ++mi)
#pragma unroll
        for (int ni = 0; ni < 4; ++ni)
          acc[mi][ni] = __builtin_amdgcn_mfma_f32_16x16x32_bf16(
              af[mi], bf[ni], acc[mi][ni], 0, 0, 0);
    }
    __syncthreads();
  }

#pragma unroll
  for (int ni = 0; ni < 4; ++ni) {
    int n = n0 + wc * 64 + ni * 16 + ln15;
    float bv = bias[n];
#pragma unroll
    for (int mi = 0; mi < 4; ++mi) {
      int mb = m0 + wr * 64 + mi * 16 + lg * 4;
#pragma unroll
      for (int j = 0; j < 4; ++j) {
        int m = mb + j;
        float v = acc[mi][ni][j] + bv;
        if (mode == 0) {
          outb[(size_t)m * N + n] = (bf16)v;
        } else if (mode == 1) {
          int bb = m >> 11, s = m & 2047, hh = n >> 6, d = n & 63;
          outb[(((size_t)bb * H_ + hh) * HD_ + d) * S_ + s] = (bf16)v;
        } else {
          outf[(size_t)m * N + n] = v;
        }
      }
    }
  }
}

// ------------------------------------------------------------- attention
// Q,K: [B*S][D] bf16 (head h at cols h*64..); Vt: [B][H][HD][S] bf16
// Ob:  [B*S][D] bf16
__global__ __launch_bounds__(256) void attn64(
    const bf16* __restrict__ Q, const bf16* __restrict__ Kb,
    const bf16* __restrict__ Vt, bf16* __restrict__ Ob) {
  const float CEXP = 0.125f * 1.44269504088896f;  // scale * log2(e)
  __shared__ bf16 Ks[64 * 64];
  __shared__ bf16 Vs[64 * 64];
  __shared__ bf16 Pl[4][16 * 72];

  int qt = blockIdx.x, bh = blockIdx.y;
  int b = bh >> 4, h = bh & 15;
  int tid = threadIdx.x, lane = tid & 63, w = tid >> 6;
  int ln15 = lane & 15, lg = lane >> 4;
  int q0 = qt * 64;

  const bf16* qrow =
      Q + (size_t)(b * S_ + q0 + w * 16 + ln15) * D_ + h * HD_ + lg * 8;
  bf16x8 qf0 = *(const bf16x8*)qrow;
  bf16x8 qf1 = *(const bf16x8*)(qrow + 32);

  f32x4 acc[4] = {};
  float mrun[4], lrun[4];
#pragma unroll
  for (int j = 0; j < 4; ++j) { mrun[j] = -1e30f; lrun[j] = 0.f; }

  const int nt = qt + 1;
  for (int kt = 0; kt < nt; ++kt) {
    int kk0 = kt * 64;
#pragma unroll
    for (int i = 0; i < 2; ++i) {
      int idx = (i * 256 + tid) * 8;
      int r = idx >> 6, c = idx & 63;
      gload16(&Ks[(size_t)(i * 256 + w * 64) * 8],
              Kb + (size_t)(b * S_ + kk0 + r) * D_ + h * HD_ + c);
      gload16(&Vs[(size_t)(i * 256 + w * 64) * 8],
              Vt + (size_t)(bh * HD_ + r) * S_ + kk0 + c);
    }
    __syncthreads();

    // QK^T : 16 q-rows x 64 kk per wave
    f32x4 sa[4] = {};
#pragma unroll
    for (int c = 0; c < 2; ++c) {
      bf16x8 qf = c ? qf1 : qf0;
#pragma unroll
      for (int ct = 0; ct < 4; ++ct) {
        bf16x8 kf = *(const bf16x8*)&Ks[(ct * 16 + ln15) * 64 + c * 32 + lg * 8];
        sa[ct] = __builtin_amdgcn_mfma_f32_16x16x32_bf16(qf, kf, sa[ct], 0, 0, 0);
      }
    }

    if (kt == qt) {  // diagonal tile: causal mask
#pragma unroll
      for (int ct = 0; ct < 4; ++ct) {
        int kkg = kk0 + ct * 16 + ln15;
#pragma unroll
        for (int j = 0; j < 4; ++j) {
          int qg = q0 + w * 16 + lg * 4 + j;
          if (kkg > qg) sa[ct][j] = -1e9f;
        }
      }
    }

    // online softmax (rows r=lg*4+j live on the 16 lanes of this lane-group)
    float pr[4][4];
#pragma unroll
    for (int j = 0; j < 4; ++j) {
      float t = fmaxf(fmaxf(sa[0][j], sa[1][j]), fmaxf(sa[2][j], sa[3][j]));
#pragma unroll
      for (int d = 1; d < 16; d <<= 1) t = fmaxf(t, __shfl_xor(t, d));
      float mnew = fmaxf(mrun[j], t);
      float rs = exp2f((mrun[j] - mnew) * CEXP);
      float ps = 0.f;
#pragma unroll
      for (int ct = 0; ct < 4; ++ct) {
        float p = exp2f((sa[ct][j] - mnew) * CEXP);
        pr[ct][j] = p;
        ps += p;
      }
#pragma unroll
      for (int d = 1; d < 16; d <<= 1) ps += __shfl_xor(ps, d);
      lrun[j] = lrun[j] * rs + ps;
      mrun[j] = mnew;
      acc[0][j] *= rs; acc[1][j] *= rs; acc[2][j] *= rs; acc[3][j] *= rs;
    }

    // P -> LDS (per-wave region, padded stride 72), then PV
    bf16* pw = &Pl[w][0];
#pragma unroll
    for (int ct = 0; ct < 4; ++ct)
#pragma unroll
      for (int j = 0; j < 4; ++j)
        pw[(lg * 4 + j) * 72 + ct * 16 + ln15] = (bf16)pr[ct][j];

#pragma unroll
    for (int c = 0; c < 2; ++c) {
      bf16x8 pa = *(const bf16x8*)&pw[ln15 * 72 + c * 32 + lg * 8];
#pragma unroll
      for (int ct = 0; ct < 4; ++ct) {
        bf16x8 vf = *(const bf16x8*)&Vs[(ct * 16 + ln15) * 64 + c * 32 + lg * 8];
        acc[ct] = __builtin_amdgcn_mfma_f32_16x16x32_bf16(pa, vf, acc[ct], 0, 0, 0);
      }
    }
    __syncthreads();
  }

#pragma unroll
  for (int ct = 0; ct < 4; ++ct)
#pragma unroll
    for (int j = 0; j < 4; ++j) {
      size_t q = (size_t)(b * S_ + q0 + w * 16 + lg * 4 + j);
      Ob[q * D_ + h * HD_ + ct * 16 + ln15] = (bf16)(acc[ct][j] / lrun[j]);
    }
}

// ---------------------------------------------------------------- launch
extern "C" void kernel_launch(void* const* d_in, const int* in_sizes, int n_in,
                              void* d_out, int out_size, void* d_ws,
                              size_t ws_size, hipStream_t stream) {
  const float* x  = (const float*)d_in[0];
  const float* Wq = (const float*)d_in[1];
  const float* bq = (const float*)d_in[2];
  const float* Wk = (const float*)d_in[3];
  const float* bk = (const float*)d_in[4];
  const float* Wv = (const float*)d_in[5];
  const float* bv = (const float*)d_in[6];
  const float* Wo = (const float*)d_in[7];
  const float* bo = (const float*)d_in[8];
  float* out = (float*)d_out;

  char* ws = (char*)d_ws;
  bf16* xb  = (bf16*)(ws);                    // 8 MB: x in bf16 [4096][1024]
  bf16* wt  = (bf16*)(ws + (8u << 20));       // 8 MB: 4x W^T bf16 [1024][1024]
  bf16* qb  = (bf16*)(ws + (16u << 20));      // 8 MB
  bf16* kb  = (bf16*)(ws + (24u << 20));      // 8 MB
  bf16* vtb = (bf16*)(ws + (32u << 20));      // 8 MB  [B][H][HD][S]
  bf16* atb = (bf16*)(ws + (40u << 20));      // 8 MB  attention out bf16

  const int M = B_ * S_;  // 4096

  cast_f32_bf16<<<dim3((M * D_) / 1024), 256, 0, stream>>>(x, xb, (M * D_) / 4);
  wtrans<<<dim3(32, 32, 4), dim3(32, 8), 0, stream>>>(Wq, Wk, Wv, Wo, wt);

  gemm128<<<dim3(8, 32), 256, 0, stream>>>(xb, wt,                bq, qb,  nullptr, M, D_, D_, 0);
  gemm128<<<dim3(8, 32), 256, 0, stream>>>(xb, wt + (1u << 20),   bk, kb,  nullptr, M, D_, D_, 0);
  gemm128<<<dim3(8, 32), 256, 0, stream>>>(xb, wt + (2u << 20),   bv, vtb, nullptr, M, D_, D_, 1);

  attn64<<<dim3(32, 32), 256, 0, stream>>>(qb, kb, vtb, atb);

  gemm128<<<dim3(8, 32), 256, 0, stream>>>(atb, wt + (3u << 20),  bo, nullptr, out, M, D_, D_, 2);
}

// Round 2
// 233.595 us; speedup vs baseline: 1.2616x; 1.2616x over previous
//
#include <hip/hip_runtime.h>
#include <hip/hip_bf16.h>
#include <stdint.h>

typedef __bf16 bf16;
typedef __bf16 bf16x8 __attribute__((ext_vector_type(8)));
typedef __bf16 bf16x4 __attribute__((ext_vector_type(4)));
typedef float f32x4 __attribute__((ext_vector_type(4)));

#define B_  2
#define S_  2048
#define D_  1024
#define H_  16
#define HD_ 64

typedef __attribute__((address_space(1))) uint32_t gu32;
typedef __attribute__((address_space(3))) uint32_t lu32;

__device__ __forceinline__ void gload16(void* lds, const void* g) {
  __builtin_amdgcn_global_load_lds((const gu32*)(uintptr_t)g,
                                   (lu32*)(uint32_t)(uintptr_t)lds,
                                   16, 0, 0);
}

// ---------------------------------------------------------------- cast x
__global__ __launch_bounds__(256) void cast_f32_bf16(
    const float* __restrict__ in, bf16* __restrict__ out, int n4) {
  int i = blockIdx.x * 256 + threadIdx.x;
  if (i < n4) {
    float4 v = ((const float4*)in)[i];
    bf16x4 o = {(bf16)v.x, (bf16)v.y, (bf16)v.z, (bf16)v.w};
    ((bf16x4*)out)[i] = o;
  }
}

// ------------------------------------------------- transpose-cast weights
__global__ __launch_bounds__(256) void wtrans(
    const float* __restrict__ w0, const float* __restrict__ w1,
    const float* __restrict__ w2, const float* __restrict__ w3,
    bf16* __restrict__ out) {
  int z = blockIdx.z;
  const float* src = (z == 0) ? w0 : (z == 1) ? w1 : (z == 2) ? w2 : w3;
  bf16* dst = out + ((size_t)z << 20);
  __shared__ float tile[32][33];
  int tx = threadIdx.x, ty = threadIdx.y;
  int x0 = blockIdx.x * 32, y0 = blockIdx.y * 32;
#pragma unroll
  for (int r = 0; r < 4; ++r)
    tile[ty + r * 8][tx] = src[(size_t)(y0 + ty + r * 8) * D_ + x0 + tx];
  __syncthreads();
#pragma unroll
  for (int r = 0; r < 4; ++r)
    dst[(size_t)(x0 + ty + r * 8) * D_ + y0 + tx] = (bf16)tile[tx][ty + r * 8];
}

// ------------------------------------------------- fused QKV projection
// A:[4096][1024] bf16, Bt:[3072][1024] bf16 (Wq^T|Wk^T|Wv^T stacked)
// seg 0 -> qb[m][n], seg 1 -> kb[m][n], seg 2 -> V^T scatter vtb
__global__ __launch_bounds__(256) void gemm_qkv(
    const bf16* __restrict__ A, const bf16* __restrict__ Bt,
    const float* __restrict__ bq, const float* __restrict__ bk,
    const float* __restrict__ bv,
    bf16* __restrict__ qb, bf16* __restrict__ kb, bf16* __restrict__ vtb) {
  __shared__ bf16 As[128 * 64];
  __shared__ bf16 Bs[128 * 64];
  const int K = D_;
  int tid = threadIdx.x;
  int lane = tid & 63, wid = tid >> 6;
  int ln15 = lane & 15, lg = lane >> 4;
  int wr = wid >> 1, wc = wid & 1;
  int m0 = blockIdx.y * 128, n0g = blockIdx.x * 128;

  f32x4 acc[4][4] = {};

  for (int k0 = 0; k0 < K; k0 += 64) {
#pragma unroll
    for (int i = 0; i < 4; ++i) {
      int idx = (i * 256 + tid) * 8;
      int r = idx >> 6, c = idx & 63;
      gload16(&As[(size_t)(i * 256 + wid * 64) * 8],
              A + (size_t)(m0 + r) * K + k0 + c);
      gload16(&Bs[(size_t)(i * 256 + wid * 64) * 8],
              Bt + (size_t)(n0g + r) * K + k0 + c);
    }
    __syncthreads();
#pragma unroll
    for (int kk = 0; kk < 64; kk += 32) {
      bf16x8 af[4], bfr[4];
#pragma unroll
      for (int t = 0; t < 4; ++t)
        af[t] = *(const bf16x8*)&As[(wr * 64 + t * 16 + ln15) * 64 + kk + lg * 8];
#pragma unroll
      for (int t = 0; t < 4; ++t)
        bfr[t] = *(const bf16x8*)&Bs[(wc * 64 + t * 16 + ln15) * 64 + kk + lg * 8];
#pragma unroll
      for (int mi = 0; mi < 4; ++mi)
#pragma unroll
        for (int ni = 0; ni < 4; ++ni)
          acc[mi][ni] = __builtin_amdgcn_mfma_f32_16x16x32_bf16(
              af[mi], bfr[ni], acc[mi][ni], 0, 0, 0);
    }
    __syncthreads();
  }

  int seg = n0g >> 10;  // block-uniform (128 | 1024)
  const float* bias = (seg == 0) ? bq : (seg == 1) ? bk : bv;
  int n0 = n0g & 1023;
#pragma unroll
  for (int ni = 0; ni < 4; ++ni) {
    int n = n0 + wc * 64 + ni * 16 + ln15;
    float bvl = bias[n];
#pragma unroll
    for (int mi = 0; mi < 4; ++mi) {
      int mb = m0 + wr * 64 + mi * 16 + lg * 4;
#pragma unroll
      for (int j = 0; j < 4; ++j) {
        int m = mb + j;
        float v = acc[mi][ni][j] + bvl;
        if (seg == 0) {
          qb[(size_t)m * D_ + n] = (bf16)v;
        } else if (seg == 1) {
          kb[(size_t)m * D_ + n] = (bf16)v;
        } else {
          int bb = m >> 11, s = m & 2047, hh = n >> 6, dd = n & 63;
          vtb[(((size_t)bb * H_ + hh) * HD_ + dd) * S_ + s] = (bf16)v;
        }
      }
    }
  }
}

// ---------------------------------------------------------------- GEMM (O-proj)
__global__ __launch_bounds__(256) void gemm128(
    const bf16* __restrict__ A, const bf16* __restrict__ Bt,
    const float* __restrict__ bias, float* __restrict__ outf,
    int M, int N, int K) {
  __shared__ bf16 As[128 * 64];
  __shared__ bf16 Bs[128 * 64];
  int tid = threadIdx.x;
  int lane = tid & 63, wid = tid >> 6;
  int ln15 = lane & 15, lg = lane >> 4;
  int wr = wid >> 1, wc = wid & 1;
  int m0 = blockIdx.y * 128, n0 = blockIdx.x * 128;

  f32x4 acc[4][4] = {};

  for (int k0 = 0; k0 < K; k0 += 64) {
#pragma unroll
    for (int i = 0; i < 4; ++i) {
      int idx = (i * 256 + tid) * 8;
      int r = idx >> 6, c = idx & 63;
      gload16(&As[(size_t)(i * 256 + wid * 64) * 8],
              A + (size_t)(m0 + r) * K + k0 + c);
      gload16(&Bs[(size_t)(i * 256 + wid * 64) * 8],
              Bt + (size_t)(n0 + r) * K + k0 + c);
    }
    __syncthreads();
#pragma unroll
    for (int kk = 0; kk < 64; kk += 32) {
      bf16x8 af[4], bfr[4];
#pragma unroll
      for (int t = 0; t < 4; ++t)
        af[t] = *(const bf16x8*)&As[(wr * 64 + t * 16 + ln15) * 64 + kk + lg * 8];
#pragma unroll
      for (int t = 0; t < 4; ++t)
        bfr[t] = *(const bf16x8*)&Bs[(wc * 64 + t * 16 + ln15) * 64 + kk + lg * 8];
#pragma unroll
      for (int mi = 0; mi < 4; ++mi)
#pragma unroll
        for (int ni = 0; ni < 4; ++ni)
          acc[mi][ni] = __builtin_amdgcn_mfma_f32_16x16x32_bf16(
              af[mi], bfr[ni], acc[mi][ni], 0, 0, 0);
    }
    __syncthreads();
  }

#pragma unroll
  for (int ni = 0; ni < 4; ++ni) {
    int n = n0 + wc * 64 + ni * 16 + ln15;
    float bvl = bias[n];
#pragma unroll
    for (int mi = 0; mi < 4; ++mi) {
      int mb = m0 + wr * 64 + mi * 16 + lg * 4;
#pragma unroll
      for (int j = 0; j < 4; ++j)
        outf[(size_t)(mb + j) * N + n] = acc[mi][ni][j] + bvl;
    }
  }
}

// ------------------------------------------------------------- attention
// Barrier-free: 4 independent waves per block, each owns 16 q-rows.
// K/V read global->register (L2-resident: 512 KB per head).
// blockIdx.x = bh (fast dim -> all qt of one head share an XCD's L2),
// blockIdx.y -> qt reversed (longest blocks dispatch first).
__global__ __launch_bounds__(256) void attn_nb(
    const bf16* __restrict__ Q, const bf16* __restrict__ Kb,
    const bf16* __restrict__ Vt, bf16* __restrict__ Ob) {
  const float CEXP = 0.125f * 1.44269504088896f;  // scale * log2(e)
  __shared__ bf16 Pl[4][16 * 72];

  int bh = blockIdx.x;
  int qt = (gridDim.y - 1) - blockIdx.y;
  int b = bh >> 4, h = bh & 15;
  int tid = threadIdx.x, lane = tid & 63, w = tid >> 6;
  int ln15 = lane & 15, lg = lane >> 4;
  int q0 = qt * 64;
  int qr = w * 16 + ln15;

  const bf16* qptr = Q + (size_t)(b * S_ + q0 + qr) * D_ + h * HD_ + lg * 8;
  bf16x8 qf0 = *(const bf16x8*)qptr;
  bf16x8 qf1 = *(const bf16x8*)(qptr + 32);

  const bf16* kbase = Kb + (size_t)(b * S_) * D_ + h * HD_;  // row stride D_
  const bf16* vbase = Vt + (size_t)bh * HD_ * S_;            // [d][s], stride S_

  f32x4 acc[4] = {};
  float mrun[4], lrun[4];
#pragma unroll
  for (int j = 0; j < 4; ++j) { mrun[j] = -1e30f; lrun[j] = 0.f; }

  bf16* pw = &Pl[w][0];

  for (int kt = 0; kt <= qt; ++kt) {
    int kk0 = kt * 64;
    // K and V fragments straight from global (issued together; compiler
    // schedules the vmcnt waits fine-grained).
    bf16x8 kf[2][4], vf[2][4];
#pragma unroll
    for (int c = 0; c < 2; ++c)
#pragma unroll
      for (int ct = 0; ct < 4; ++ct)
        kf[c][ct] = *(const bf16x8*)(kbase +
            (size_t)(kk0 + ct * 16 + ln15) * D_ + c * 32 + lg * 8);
#pragma unroll
    for (int c = 0; c < 2; ++c)
#pragma unroll
      for (int ct = 0; ct < 4; ++ct)
        vf[c][ct] = *(const bf16x8*)(vbase +
            (size_t)(ct * 16 + ln15) * S_ + kk0 + c * 32 + lg * 8);

    // QK^T
    f32x4 sa[4] = {};
    __builtin_amdgcn_s_setprio(1);
#pragma unroll
    for (int c = 0; c < 2; ++c) {
      bf16x8 qf = c ? qf1 : qf0;
#pragma unroll
      for (int ct = 0; ct < 4; ++ct)
        sa[ct] = __builtin_amdgcn_mfma_f32_16x16x32_bf16(qf, kf[c][ct], sa[ct], 0, 0, 0);
    }
    __builtin_amdgcn_s_setprio(0);

    if (kt == qt) {  // causal mask on diagonal tile
#pragma unroll
      for (int ct = 0; ct < 4; ++ct) {
        int kkg = kk0 + ct * 16 + ln15;
#pragma unroll
        for (int j = 0; j < 4; ++j) {
          int qg = q0 + w * 16 + lg * 4 + j;
          if (kkg > qg) sa[ct][j] = -1e9f;
        }
      }
    }

    // online softmax: row r = lg*4+j lives across the 16 lanes of this group
    float pr[4][4];
#pragma unroll
    for (int j = 0; j < 4; ++j) {
      float t = fmaxf(fmaxf(sa[0][j], sa[1][j]), fmaxf(sa[2][j], sa[3][j]));
#pragma unroll
      for (int d = 1; d < 16; d <<= 1) t = fmaxf(t, __shfl_xor(t, d));
      float mnew = fmaxf(mrun[j], t);
      float rs = exp2f((mrun[j] - mnew) * CEXP);
      float ps = 0.f;
#pragma unroll
      for (int ct = 0; ct < 4; ++ct) {
        float p = exp2f((sa[ct][j] - mnew) * CEXP);
        pr[ct][j] = p;
        ps += p;
      }
#pragma unroll
      for (int d = 1; d < 16; d <<= 1) ps += __shfl_xor(ps, d);
      lrun[j] = lrun[j] * rs + ps;
      mrun[j] = mnew;
      acc[0][j] *= rs; acc[1][j] *= rs; acc[2][j] *= rs; acc[3][j] *= rs;
    }

    // P -> per-wave LDS (stride 72: bank-friendly), then PV
#pragma unroll
    for (int ct = 0; ct < 4; ++ct)
#pragma unroll
      for (int j = 0; j < 4; ++j)
        pw[(lg * 4 + j) * 72 + ct * 16 + ln15] = (bf16)pr[ct][j];

    __builtin_amdgcn_s_setprio(1);
#pragma unroll
    for (int c = 0; c < 2; ++c) {
      bf16x8 pa = *(const bf16x8*)&pw[ln15 * 72 + c * 32 + lg * 8];
#pragma unroll
      for (int ct = 0; ct < 4; ++ct)
        acc[ct] = __builtin_amdgcn_mfma_f32_16x16x32_bf16(pa, vf[c][ct], acc[ct], 0, 0, 0);
    }
    __builtin_amdgcn_s_setprio(0);
  }

#pragma unroll
  for (int ct = 0; ct < 4; ++ct)
#pragma unroll
    for (int j = 0; j < 4; ++j) {
      size_t q = (size_t)(b * S_ + q0 + w * 16 + lg * 4 + j);
      Ob[q * D_ + h * HD_ + ct * 16 + ln15] = (bf16)(acc[ct][j] / lrun[j]);
    }
}

// ---------------------------------------------------------------- launch
extern "C" void kernel_launch(void* const* d_in, const int* in_sizes, int n_in,
                              void* d_out, int out_size, void* d_ws,
                              size_t ws_size, hipStream_t stream) {
  const float* x  = (const float*)d_in[0];
  const float* Wq = (const float*)d_in[1];
  const float* bq = (const float*)d_in[2];
  const float* Wk = (const float*)d_in[3];
  const float* bk = (const float*)d_in[4];
  const float* Wv = (const float*)d_in[5];
  const float* bv = (const float*)d_in[6];
  const float* Wo = (const float*)d_in[7];
  const float* bo = (const float*)d_in[8];
  float* out = (float*)d_out;

  char* ws = (char*)d_ws;
  bf16* xb  = (bf16*)(ws);                    // 8 MB: x bf16 [4096][1024]
  bf16* wt  = (bf16*)(ws + (8u << 20));       // 8 MB: Wq^T|Wk^T|Wv^T|Wo^T bf16
  bf16* qb  = (bf16*)(ws + (16u << 20));      // 8 MB
  bf16* kb  = (bf16*)(ws + (24u << 20));      // 8 MB
  bf16* vtb = (bf16*)(ws + (32u << 20));      // 8 MB  [B][H][HD][S]
  bf16* atb = (bf16*)(ws + (40u << 20));      // 8 MB  attention out bf16

  const int M = B_ * S_;  // 4096

  cast_f32_bf16<<<dim3((M * D_) / 1024), 256, 0, stream>>>(x, xb, (M * D_) / 4);
  wtrans<<<dim3(32, 32, 4), dim3(32, 8), 0, stream>>>(Wq, Wk, Wv, Wo, wt);

  // fused QKV: Bt = [3072][1024] (wt slabs 0..2 are contiguous)
  gemm_qkv<<<dim3(24, 32), 256, 0, stream>>>(xb, wt, bq, bk, bv, qb, kb, vtb);

  attn_nb<<<dim3(32, 32), 256, 0, stream>>>(qb, kb, vtb, atb);

  gemm128<<<dim3(8, 32), 256, 0, stream>>>(atb, wt + (3u << 20), bo, out, M, D_, D_);
}

// Round 3
// 232.934 us; speedup vs baseline: 1.2651x; 1.0028x over previous
//
#include <hip/hip_runtime.h>
#include <hip/hip_bf16.h>
#include <stdint.h>

typedef __bf16 bf16;
typedef __bf16 bf16x8 __attribute__((ext_vector_type(8)));
typedef __bf16 bf16x4 __attribute__((ext_vector_type(4)));
typedef float f32x4 __attribute__((ext_vector_type(4)));

#define B_  2
#define S_  2048
#define D_  1024
#define H_  16
#define HD_ 64

typedef __attribute__((address_space(1))) uint32_t gu32;
typedef __attribute__((address_space(3))) uint32_t lu32;

__device__ __forceinline__ void gload16(void* lds, const void* g) {
  __builtin_amdgcn_global_load_lds((const gu32*)(uintptr_t)g,
                                   (lu32*)(uint32_t)(uintptr_t)lds,
                                   16, 0, 0);
}

// ---------------------------------------------------------------- cast x
__global__ __launch_bounds__(256) void cast_f32_bf16(
    const float* __restrict__ in, bf16* __restrict__ out, int n4) {
  int i = blockIdx.x * 256 + threadIdx.x;
  if (i < n4) {
    float4 v = ((const float4*)in)[i];
    bf16x4 o = {(bf16)v.x, (bf16)v.y, (bf16)v.z, (bf16)v.w};
    ((bf16x4*)out)[i] = o;
  }
}

// ------------------------------------------------- transpose-cast weights
__global__ __launch_bounds__(256) void wtrans(
    const float* __restrict__ w0, const float* __restrict__ w1,
    const float* __restrict__ w2, const float* __restrict__ w3,
    bf16* __restrict__ out) {
  int z = blockIdx.z;
  const float* src = (z == 0) ? w0 : (z == 1) ? w1 : (z == 2) ? w2 : w3;
  bf16* dst = out + ((size_t)z << 20);
  __shared__ float tile[32][33];
  int tx = threadIdx.x, ty = threadIdx.y;
  int x0 = blockIdx.x * 32, y0 = blockIdx.y * 32;
#pragma unroll
  for (int r = 0; r < 4; ++r)
    tile[ty + r * 8][tx] = src[(size_t)(y0 + ty + r * 8) * D_ + x0 + tx];
  __syncthreads();
#pragma unroll
  for (int r = 0; r < 4; ++r)
    dst[(size_t)(x0 + ty + r * 8) * D_ + y0 + tx] = (bf16)tile[tx][ty + r * 8];
}

// ------------------------------------------------- fused QKV projection
// A:[4096][1024] bf16, Bt:[3072][1024] bf16 (Wq^T|Wk^T|Wv^T stacked)
// seg 0 -> qb[m][n], seg 1 -> kb[m][n], seg 2 -> V^T scatter vtb
__global__ __launch_bounds__(256) void gemm_qkv(
    const bf16* __restrict__ A, const bf16* __restrict__ Bt,
    const float* __restrict__ bq, const float* __restrict__ bk,
    const float* __restrict__ bv,
    bf16* __restrict__ qb, bf16* __restrict__ kb, bf16* __restrict__ vtb) {
  __shared__ bf16 As[128 * 64];
  __shared__ bf16 Bs[128 * 64];
  const int K = D_;
  int tid = threadIdx.x;
  int lane = tid & 63, wid = tid >> 6;
  int ln15 = lane & 15, lg = lane >> 4;
  int wr = wid >> 1, wc = wid & 1;
  int m0 = blockIdx.y * 128, n0g = blockIdx.x * 128;

  f32x4 acc[4][4] = {};

  for (int k0 = 0; k0 < K; k0 += 64) {
#pragma unroll
    for (int i = 0; i < 4; ++i) {
      int idx = (i * 256 + tid) * 8;
      int r = idx >> 6, c = idx & 63;
      gload16(&As[(size_t)(i * 256 + wid * 64) * 8],
              A + (size_t)(m0 + r) * K + k0 + c);
      gload16(&Bs[(size_t)(i * 256 + wid * 64) * 8],
              Bt + (size_t)(n0g + r) * K + k0 + c);
    }
    __syncthreads();
#pragma unroll
    for (int kk = 0; kk < 64; kk += 32) {
      bf16x8 af[4], bfr[4];
#pragma unroll
      for (int t = 0; t < 4; ++t)
        af[t] = *(const bf16x8*)&As[(wr * 64 + t * 16 + ln15) * 64 + kk + lg * 8];
#pragma unroll
      for (int t = 0; t < 4; ++t)
        bfr[t] = *(const bf16x8*)&Bs[(wc * 64 + t * 16 + ln15) * 64 + kk + lg * 8];
#pragma unroll
      for (int mi = 0; mi < 4; ++mi)
#pragma unroll
        for (int ni = 0; ni < 4; ++ni)
          acc[mi][ni] = __builtin_amdgcn_mfma_f32_16x16x32_bf16(
              af[mi], bfr[ni], acc[mi][ni], 0, 0, 0);
    }
    __syncthreads();
  }

  int seg = n0g >> 10;  // block-uniform (128 | 1024)
  const float* bias = (seg == 0) ? bq : (seg == 1) ? bk : bv;
  int n0 = n0g & 1023;
#pragma unroll
  for (int ni = 0; ni < 4; ++ni) {
    int n = n0 + wc * 64 + ni * 16 + ln15;
    float bvl = bias[n];
#pragma unroll
    for (int mi = 0; mi < 4; ++mi) {
      int mb = m0 + wr * 64 + mi * 16 + lg * 4;
#pragma unroll
      for (int j = 0; j < 4; ++j) {
        int m = mb + j;
        float v = acc[mi][ni][j] + bvl;
        if (seg == 0) {
          qb[(size_t)m * D_ + n] = (bf16)v;
        } else if (seg == 1) {
          kb[(size_t)m * D_ + n] = (bf16)v;
        } else {
          int bb = m >> 11, s = m & 2047, hh = n >> 6, dd = n & 63;
          vtb[(((size_t)bb * H_ + hh) * HD_ + dd) * S_ + s] = (bf16)v;
        }
      }
    }
  }
}

// ---------------------------------------------------------------- GEMM (O-proj)
__global__ __launch_bounds__(256) void gemm128(
    const bf16* __restrict__ A, const bf16* __restrict__ Bt,
    const float* __restrict__ bias, float* __restrict__ outf,
    int M, int N, int K) {
  __shared__ bf16 As[128 * 64];
  __shared__ bf16 Bs[128 * 64];
  int tid = threadIdx.x;
  int lane = tid & 63, wid = tid >> 6;
  int ln15 = lane & 15, lg = lane >> 4;
  int wr = wid >> 1, wc = wid & 1;
  int m0 = blockIdx.y * 128, n0 = blockIdx.x * 128;

  f32x4 acc[4][4] = {};

  for (int k0 = 0; k0 < K; k0 += 64) {
#pragma unroll
    for (int i = 0; i < 4; ++i) {
      int idx = (i * 256 + tid) * 8;
      int r = idx >> 6, c = idx & 63;
      gload16(&As[(size_t)(i * 256 + wid * 64) * 8],
              A + (size_t)(m0 + r) * K + k0 + c);
      gload16(&Bs[(size_t)(i * 256 + wid * 64) * 8],
              Bt + (size_t)(n0 + r) * K + k0 + c);
    }
    __syncthreads();
#pragma unroll
    for (int kk = 0; kk < 64; kk += 32) {
      bf16x8 af[4], bfr[4];
#pragma unroll
      for (int t = 0; t < 4; ++t)
        af[t] = *(const bf16x8*)&As[(wr * 64 + t * 16 + ln15) * 64 + kk + lg * 8];
#pragma unroll
      for (int t = 0; t < 4; ++t)
        bfr[t] = *(const bf16x8*)&Bs[(wc * 64 + t * 16 + ln15) * 64 + kk + lg * 8];
#pragma unroll
      for (int mi = 0; mi < 4; ++mi)
#pragma unroll
        for (int ni = 0; ni < 4; ++ni)
          acc[mi][ni] = __builtin_amdgcn_mfma_f32_16x16x32_bf16(
              af[mi], bfr[ni], acc[mi][ni], 0, 0, 0);
    }
    __syncthreads();
  }

#pragma unroll
  for (int ni = 0; ni < 4; ++ni) {
    int n = n0 + wc * 64 + ni * 16 + ln15;
    float bvl = bias[n];
#pragma unroll
    for (int mi = 0; mi < 4; ++mi) {
      int mb = m0 + wr * 64 + mi * 16 + lg * 4;
#pragma unroll
      for (int j = 0; j < 4; ++j)
        outf[(size_t)(mb + j) * N + n] = acc[mi][ni][j] + bvl;
    }
  }
}

// ------------------------------------------------------------- attention
// Barrier-free, software-pipelined: K-fragments for tile kt+1 prefetched
// into a ping-pong register buffer while tile kt computes. V issued at the
// top of each compute body (first use is ~400 cyc later, after softmax).
__global__ __launch_bounds__(256) void attn_nb(
    const bf16* __restrict__ Q, const bf16* __restrict__ Kb,
    const bf16* __restrict__ Vt, bf16* __restrict__ Ob) {
  const float CEXP = 0.125f * 1.44269504088896f;  // scale * log2(e)
  __shared__ bf16 Pl[4][16 * 72];

  int bh = blockIdx.x;
  int qt = (gridDim.y - 1) - blockIdx.y;
  int b = bh >> 4, h = bh & 15;
  int tid = threadIdx.x, lane = tid & 63, w = tid >> 6;
  int ln15 = lane & 15, lg = lane >> 4;
  int q0 = qt * 64;
  int qr = w * 16 + ln15;

  const bf16* qptr = Q + (size_t)(b * S_ + q0 + qr) * D_ + h * HD_ + lg * 8;
  bf16x8 qf0 = *(const bf16x8*)qptr;
  bf16x8 qf1 = *(const bf16x8*)(qptr + 32);

  const bf16* kbase = Kb + (size_t)(b * S_) * D_ + h * HD_;  // row stride D_
  const bf16* vbase = Vt + (size_t)bh * HD_ * S_;            // [d][s], stride S_

  f32x4 acc[4] = {};
  float mrun[4], lrun[4];
#pragma unroll
  for (int j = 0; j < 4; ++j) { mrun[j] = -1e30f; lrun[j] = 0.f; }

  bf16* pw = &Pl[w][0];

  auto loadk = [&](bf16x8 (&kf)[2][4], int kt) {
    int kk0 = kt * 64;
#pragma unroll
    for (int c = 0; c < 2; ++c)
#pragma unroll
      for (int ct = 0; ct < 4; ++ct)
        kf[c][ct] = *(const bf16x8*)(kbase +
            (size_t)(kk0 + ct * 16 + ln15) * D_ + c * 32 + lg * 8);
  };

  auto compute = [&](bf16x8 (&kf)[2][4], int kt) {
    int kk0 = kt * 64;
    // V for this tile: issued now, consumed after softmax (latency hidden)
    bf16x8 vf[2][4];
#pragma unroll
    for (int c = 0; c < 2; ++c)
#pragma unroll
      for (int ct = 0; ct < 4; ++ct)
        vf[c][ct] = *(const bf16x8*)(vbase +
            (size_t)(ct * 16 + ln15) * S_ + kk0 + c * 32 + lg * 8);

    // QK^T (K-fragments already resident from the prefetch)
    f32x4 sa[4] = {};
    __builtin_amdgcn_s_setprio(1);
#pragma unroll
    for (int c = 0; c < 2; ++c) {
      bf16x8 qf = c ? qf1 : qf0;
#pragma unroll
      for (int ct = 0; ct < 4; ++ct)
        sa[ct] = __builtin_amdgcn_mfma_f32_16x16x32_bf16(qf, kf[c][ct], sa[ct], 0, 0, 0);
    }
    __builtin_amdgcn_s_setprio(0);

    if (kt == qt) {  // causal mask on diagonal tile
#pragma unroll
      for (int ct = 0; ct < 4; ++ct) {
        int kkg = kk0 + ct * 16 + ln15;
#pragma unroll
        for (int j = 0; j < 4; ++j) {
          int qg = q0 + w * 16 + lg * 4 + j;
          if (kkg > qg) sa[ct][j] = -1e9f;
        }
      }
    }

    // online softmax: row r = lg*4+j lives across the 16 lanes of this group
    float pr[4][4];
#pragma unroll
    for (int j = 0; j < 4; ++j) {
      float t = fmaxf(fmaxf(sa[0][j], sa[1][j]), fmaxf(sa[2][j], sa[3][j]));
#pragma unroll
      for (int d = 1; d < 16; d <<= 1) t = fmaxf(t, __shfl_xor(t, d));
      float mnew = fmaxf(mrun[j], t);
      float rs = exp2f((mrun[j] - mnew) * CEXP);
      float ps = 0.f;
#pragma unroll
      for (int ct = 0; ct < 4; ++ct) {
        float p = exp2f((sa[ct][j] - mnew) * CEXP);
        pr[ct][j] = p;
        ps += p;
      }
#pragma unroll
      for (int d = 1; d < 16; d <<= 1) ps += __shfl_xor(ps, d);
      lrun[j] = lrun[j] * rs + ps;
      mrun[j] = mnew;
      acc[0][j] *= rs; acc[1][j] *= rs; acc[2][j] *= rs; acc[3][j] *= rs;
    }

    // P -> per-wave LDS (stride 72), then PV
#pragma unroll
    for (int ct = 0; ct < 4; ++ct)
#pragma unroll
      for (int j = 0; j < 4; ++j)
        pw[(lg * 4 + j) * 72 + ct * 16 + ln15] = (bf16)pr[ct][j];

    __builtin_amdgcn_s_setprio(1);
#pragma unroll
    for (int c = 0; c < 2; ++c) {
      bf16x8 pa = *(const bf16x8*)&pw[ln15 * 72 + c * 32 + lg * 8];
#pragma unroll
      for (int ct = 0; ct < 4; ++ct)
        acc[ct] = __builtin_amdgcn_mfma_f32_16x16x32_bf16(pa, vf[c][ct], acc[ct], 0, 0, 0);
    }
    __builtin_amdgcn_s_setprio(0);
  };

  const int nt = qt + 1;
  bf16x8 kfA[2][4], kfB[2][4];
  loadk(kfA, 0);
  int kt = 0;
  while (kt + 2 <= nt) {
    loadk(kfB, kt + 1);          // prefetch next while computing current
    compute(kfA, kt);
    if (kt + 2 < nt) loadk(kfA, kt + 2);
    compute(kfB, kt + 1);
    kt += 2;
  }
  if (kt < nt) compute(kfA, kt);

#pragma unroll
  for (int ct = 0; ct < 4; ++ct)
#pragma unroll
    for (int j = 0; j < 4; ++j) {
      size_t q = (size_t)(b * S_ + q0 + w * 16 + lg * 4 + j);
      Ob[q * D_ + h * HD_ + ct * 16 + ln15] = (bf16)(acc[ct][j] / lrun[j]);
    }
}

// ---------------------------------------------------------------- launch
extern "C" void kernel_launch(void* const* d_in, const int* in_sizes, int n_in,
                              void* d_out, int out_size, void* d_ws,
                              size_t ws_size, hipStream_t stream) {
  const float* x  = (const float*)d_in[0];
  const float* Wq = (const float*)d_in[1];
  const float* bq = (const float*)d_in[2];
  const float* Wk = (const float*)d_in[3];
  const float* bk = (const float*)d_in[4];
  const float* Wv = (const float*)d_in[5];
  const float* bv = (const float*)d_in[6];
  const float* Wo = (const float*)d_in[7];
  const float* bo = (const float*)d_in[8];
  float* out = (float*)d_out;

  char* ws = (char*)d_ws;
  bf16* xb  = (bf16*)(ws);                    // 8 MB: x bf16 [4096][1024]
  bf16* wt  = (bf16*)(ws + (8u << 20));       // 8 MB: Wq^T|Wk^T|Wv^T|Wo^T bf16
  bf16* qb  = (bf16*)(ws + (16u << 20));      // 8 MB
  bf16* kb  = (bf16*)(ws + (24u << 20));      // 8 MB
  bf16* vtb = (bf16*)(ws + (32u << 20));      // 8 MB  [B][H][HD][S]
  bf16* atb = (bf16*)(ws + (40u << 20));      // 8 MB  attention out bf16

  const int M = B_ * S_;  // 4096

  cast_f32_bf16<<<dim3((M * D_) / 1024), 256, 0, stream>>>(x, xb, (M * D_) / 4);
  wtrans<<<dim3(32, 32, 4), dim3(32, 8), 0, stream>>>(Wq, Wk, Wv, Wo, wt);

  // fused QKV: Bt = [3072][1024] (wt slabs 0..2 are contiguous)
  gemm_qkv<<<dim3(24, 32), 256, 0, stream>>>(xb, wt, bq, bk, bv, qb, kb, vtb);

  attn_nb<<<dim3(32, 32), 256, 0, stream>>>(qb, kb, vtb, atb);

  gemm128<<<dim3(8, 32), 256, 0, stream>>>(atb, wt + (3u << 20), bo, out, M, D_, D_);
}

// Round 4
// 232.122 us; speedup vs baseline: 1.2696x; 1.0035x over previous
//
#include <hip/hip_runtime.h>
#include <hip/hip_bf16.h>
#include <stdint.h>

typedef __bf16 bf16;
typedef __bf16 bf16x8 __attribute__((ext_vector_type(8)));
typedef __bf16 bf16x4 __attribute__((ext_vector_type(4)));
typedef float f32x4 __attribute__((ext_vector_type(4)));

#define B_  2
#define S_  2048
#define D_  1024
#define H_  16
#define HD_ 64

typedef __attribute__((address_space(1))) uint32_t gu32;
typedef __attribute__((address_space(3))) uint32_t lu32;

__device__ __forceinline__ void gload16(void* lds, const void* g) {
  __builtin_amdgcn_global_load_lds((const gu32*)(uintptr_t)g,
                                   (lu32*)(uint32_t)(uintptr_t)lds,
                                   16, 0, 0);
}

// ---------------------------------------------------------------- cast x
__global__ __launch_bounds__(256) void cast_f32_bf16(
    const float* __restrict__ in, bf16* __restrict__ out, int n4) {
  int i = blockIdx.x * 256 + threadIdx.x;
  if (i < n4) {
    float4 v = ((const float4*)in)[i];
    bf16x4 o = {(bf16)v.x, (bf16)v.y, (bf16)v.z, (bf16)v.w};
    ((bf16x4*)out)[i] = o;
  }
}

// ------------------------------------------------- transpose-cast weights
__global__ __launch_bounds__(256) void wtrans(
    const float* __restrict__ w0, const float* __restrict__ w1,
    const float* __restrict__ w2, const float* __restrict__ w3,
    bf16* __restrict__ out) {
  int z = blockIdx.z;
  const float* src = (z == 0) ? w0 : (z == 1) ? w1 : (z == 2) ? w2 : w3;
  bf16* dst = out + ((size_t)z << 20);
  __shared__ float tile[32][33];
  int tx = threadIdx.x, ty = threadIdx.y;
  int x0 = blockIdx.x * 32, y0 = blockIdx.y * 32;
#pragma unroll
  for (int r = 0; r < 4; ++r)
    tile[ty + r * 8][tx] = src[(size_t)(y0 + ty + r * 8) * D_ + x0 + tx];
  __syncthreads();
#pragma unroll
  for (int r = 0; r < 4; ++r)
    dst[(size_t)(x0 + ty + r * 8) * D_ + y0 + tx] = (bf16)tile[tx][ty + r * 8];
}

// ------------------------------------------------- fused QKV projection
__global__ __launch_bounds__(256) void gemm_qkv(
    const bf16* __restrict__ A, const bf16* __restrict__ Bt,
    const float* __restrict__ bq, const float* __restrict__ bk,
    const float* __restrict__ bv,
    bf16* __restrict__ qb, bf16* __restrict__ kb, bf16* __restrict__ vtb) {
  __shared__ bf16 As[128 * 64];
  __shared__ bf16 Bs[128 * 64];
  const int K = D_;
  int tid = threadIdx.x;
  int lane = tid & 63, wid = tid >> 6;
  int ln15 = lane & 15, lg = lane >> 4;
  int wr = wid >> 1, wc = wid & 1;
  int m0 = blockIdx.y * 128, n0g = blockIdx.x * 128;

  f32x4 acc[4][4] = {};

  for (int k0 = 0; k0 < K; k0 += 64) {
#pragma unroll
    for (int i = 0; i < 4; ++i) {
      int idx = (i * 256 + tid) * 8;
      int r = idx >> 6, c = idx & 63;
      gload16(&As[(size_t)(i * 256 + wid * 64) * 8],
              A + (size_t)(m0 + r) * K + k0 + c);
      gload16(&Bs[(size_t)(i * 256 + wid * 64) * 8],
              Bt + (size_t)(n0g + r) * K + k0 + c);
    }
    __syncthreads();
#pragma unroll
    for (int kk = 0; kk < 64; kk += 32) {
      bf16x8 af[4], bfr[4];
#pragma unroll
      for (int t = 0; t < 4; ++t)
        af[t] = *(const bf16x8*)&As[(wr * 64 + t * 16 + ln15) * 64 + kk + lg * 8];
#pragma unroll
      for (int t = 0; t < 4; ++t)
        bfr[t] = *(const bf16x8*)&Bs[(wc * 64 + t * 16 + ln15) * 64 + kk + lg * 8];
#pragma unroll
      for (int mi = 0; mi < 4; ++mi)
#pragma unroll
        for (int ni = 0; ni < 4; ++ni)
          acc[mi][ni] = __builtin_amdgcn_mfma_f32_16x16x32_bf16(
              af[mi], bfr[ni], acc[mi][ni], 0, 0, 0);
    }
    __syncthreads();
  }

  int seg = n0g >> 10;  // block-uniform (128 | 1024)
  const float* bias = (seg == 0) ? bq : (seg == 1) ? bk : bv;
  int n0 = n0g & 1023;
#pragma unroll
  for (int ni = 0; ni < 4; ++ni) {
    int n = n0 + wc * 64 + ni * 16 + ln15;
    float bvl = bias[n];
#pragma unroll
    for (int mi = 0; mi < 4; ++mi) {
      int mb = m0 + wr * 64 + mi * 16 + lg * 4;
#pragma unroll
      for (int j = 0; j < 4; ++j) {
        int m = mb + j;
        float v = acc[mi][ni][j] + bvl;
        if (seg == 0) {
          qb[(size_t)m * D_ + n] = (bf16)v;
        } else if (seg == 1) {
          kb[(size_t)m * D_ + n] = (bf16)v;
        } else {
          int bb = m >> 11, s = m & 2047, hh = n >> 6, dd = n & 63;
          vtb[(((size_t)bb * H_ + hh) * HD_ + dd) * S_ + s] = (bf16)v;
        }
      }
    }
  }
}

// ---------------------------------------------------------------- GEMM (O-proj)
__global__ __launch_bounds__(256) void gemm128(
    const bf16* __restrict__ A, const bf16* __restrict__ Bt,
    const float* __restrict__ bias, float* __restrict__ outf,
    int M, int N, int K) {
  __shared__ bf16 As[128 * 64];
  __shared__ bf16 Bs[128 * 64];
  int tid = threadIdx.x;
  int lane = tid & 63, wid = tid >> 6;
  int ln15 = lane & 15, lg = lane >> 4;
  int wr = wid >> 1, wc = wid & 1;
  int m0 = blockIdx.y * 128, n0 = blockIdx.x * 128;

  f32x4 acc[4][4] = {};

  for (int k0 = 0; k0 < K; k0 += 64) {
#pragma unroll
    for (int i = 0; i < 4; ++i) {
      int idx = (i * 256 + tid) * 8;
      int r = idx >> 6, c = idx & 63;
      gload16(&As[(size_t)(i * 256 + wid * 64) * 8],
              A + (size_t)(m0 + r) * K + k0 + c);
      gload16(&Bs[(size_t)(i * 256 + wid * 64) * 8],
              Bt + (size_t)(n0 + r) * K + k0 + c);
    }
    __syncthreads();
#pragma unroll
    for (int kk = 0; kk < 64; kk += 32) {
      bf16x8 af[4], bfr[4];
#pragma unroll
      for (int t = 0; t < 4; ++t)
        af[t] = *(const bf16x8*)&As[(wr * 64 + t * 16 + ln15) * 64 + kk + lg * 8];
#pragma unroll
      for (int t = 0; t < 4; ++t)
        bfr[t] = *(const bf16x8*)&Bs[(wc * 64 + t * 16 + ln15) * 64 + kk + lg * 8];
#pragma unroll
      for (int mi = 0; mi < 4; ++mi)
#pragma unroll
        for (int ni = 0; ni < 4; ++ni)
          acc[mi][ni] = __builtin_amdgcn_mfma_f32_16x16x32_bf16(
              af[mi], bfr[ni], acc[mi][ni], 0, 0, 0);
    }
    __syncthreads();
  }

#pragma unroll
  for (int ni = 0; ni < 4; ++ni) {
    int n = n0 + wc * 64 + ni * 16 + ln15;
    float bvl = bias[n];
#pragma unroll
    for (int mi = 0; mi < 4; ++mi) {
      int mb = m0 + wr * 64 + mi * 16 + lg * 4;
#pragma unroll
      for (int j = 0; j < 4; ++j)
        outf[(size_t)(mb + j) * N + n] = acc[mi][ni][j] + bvl;
    }
  }
}

// ------------------------------------------------------------- attention
// Swapped-operand flash attention: S^T = mfma(K,Q) puts q on lane&15 and
// k on lg*4+j -> softmax is lane-local (15-op trees + 2 shfl_xor instead
// of 8 chained 4-step shfl reductions). PV also swapped: O^T = mfma(V^T,P).
// Barrier-free; 4 independent waves x 16 q-rows; K/V L2-resident.
__global__ __launch_bounds__(256) void attn_nb(
    const bf16* __restrict__ Q, const bf16* __restrict__ Kb,
    const bf16* __restrict__ Vt, bf16* __restrict__ Ob) {
  const float CEXP = 0.125f * 1.44269504088896f;  // scale * log2(e)
  __shared__ bf16 Pl[4][16 * 72];

  int bh = blockIdx.x;
  int qt = (gridDim.y - 1) - blockIdx.y;
  int b = bh >> 4, h = bh & 15;
  int tid = threadIdx.x, lane = tid & 63, w = tid >> 6;
  int ln15 = lane & 15, lg = lane >> 4;
  int q0 = qt * 64;
  int q = q0 + w * 16 + ln15;  // this lane's q-row

  const bf16* qptr = Q + (size_t)(b * S_ + q) * D_ + h * HD_ + lg * 8;
  bf16x8 qf0 = *(const bf16x8*)qptr;
  bf16x8 qf1 = *(const bf16x8*)(qptr + 32);

  const bf16* kbase = Kb + (size_t)(b * S_) * D_ + h * HD_;  // row stride D_
  const bf16* vbase = Vt + (size_t)bh * HD_ * S_;            // [d][s], stride S_

  // acc[ct][j] = O^T[d = ct*16 + lg*4 + j][q]
  f32x4 acc[4] = {};
  float mrun = -1e30f, lrun = 0.f;

  bf16* pw = &Pl[w][0];

  auto loadk = [&](bf16x8 (&kf)[2][4], int kt) {
    int kk0 = kt * 64;
#pragma unroll
    for (int c = 0; c < 2; ++c)
#pragma unroll
      for (int ct = 0; ct < 4; ++ct)
        kf[c][ct] = *(const bf16x8*)(kbase +
            (size_t)(kk0 + ct * 16 + ln15) * D_ + c * 32 + lg * 8);
  };

  auto compute = [&](bf16x8 (&kf)[2][4], int kt) {
    int kk0 = kt * 64;
    // V^T fragments (A-operand of swapped PV); first use after softmax
    bf16x8 vf[2][4];
#pragma unroll
    for (int c = 0; c < 2; ++c)
#pragma unroll
      for (int ct = 0; ct < 4; ++ct)
        vf[c][ct] = *(const bf16x8*)(vbase +
            (size_t)(ct * 16 + ln15) * S_ + kk0 + c * 32 + lg * 8);

    // S^T = K Q^T : sa[ct][j] = S[k = kk0+ct*16+lg*4+j][q]
    f32x4 sa[4] = {};
    __builtin_amdgcn_s_setprio(1);
#pragma unroll
    for (int c = 0; c < 2; ++c) {
      bf16x8 qf = c ? qf1 : qf0;
#pragma unroll
      for (int ct = 0; ct < 4; ++ct)
        sa[ct] = __builtin_amdgcn_mfma_f32_16x16x32_bf16(kf[c][ct], qf, sa[ct], 0, 0, 0);
    }
    __builtin_amdgcn_s_setprio(0);

    if (kt == qt) {  // causal mask on diagonal tile
#pragma unroll
      for (int ct = 0; ct < 4; ++ct) {
        int kb0 = kk0 + ct * 16 + lg * 4;
#pragma unroll
        for (int j = 0; j < 4; ++j)
          if (kb0 + j > q) sa[ct][j] = -1e9f;
      }
    }

    // lane-local softmax over this lane's 16 scores, then 2 shfl across lg
    f32x4 mx = sa[0];
    mx = __builtin_elementwise_max(mx, sa[1]);
    mx = __builtin_elementwise_max(mx, sa[2]);
    mx = __builtin_elementwise_max(mx, sa[3]);
    float t = fmaxf(fmaxf(mx[0], mx[1]), fmaxf(mx[2], mx[3]));
    t = fmaxf(t, __shfl_xor(t, 16));
    t = fmaxf(t, __shfl_xor(t, 32));
    float mnew = fmaxf(mrun, t);
    float rs = exp2f((mrun - mnew) * CEXP);

    float p[4][4];
    float ps0 = 0.f, ps1 = 0.f;
#pragma unroll
    for (int ct = 0; ct < 4; ++ct) {
#pragma unroll
      for (int j = 0; j < 4; ++j)
        p[ct][j] = exp2f((sa[ct][j] - mnew) * CEXP);
      ps0 += p[ct][0] + p[ct][1];
      ps1 += p[ct][2] + p[ct][3];
    }
    float ps = ps0 + ps1;
    ps += __shfl_xor(ps, 16);
    ps += __shfl_xor(ps, 32);
    lrun = lrun * rs + ps;
    mrun = mnew;
#pragma unroll
    for (int ct = 0; ct < 4; ++ct)
#pragma unroll
      for (int j = 0; j < 4; ++j) acc[ct][j] *= rs;

    // P -> LDS: lane owns row q=ln15, keys ct*16+lg*4..+3 (packed 8B writes)
#pragma unroll
    for (int ct = 0; ct < 4; ++ct) {
      bf16x4 pk = {(bf16)p[ct][0], (bf16)p[ct][1], (bf16)p[ct][2], (bf16)p[ct][3]};
      *(bf16x4*)&pw[ln15 * 72 + ct * 16 + lg * 4] = pk;
    }

    // PV (swapped): acc[ct] += V^T[ct-rows][keys] x P[keys][q]
    __builtin_amdgcn_s_setprio(1);
#pragma unroll
    for (int c = 0; c < 2; ++c) {
      bf16x8 pa = *(const bf16x8*)&pw[ln15 * 72 + c * 32 + lg * 8];
#pragma unroll
      for (int ct = 0; ct < 4; ++ct)
        acc[ct] = __builtin_amdgcn_mfma_f32_16x16x32_bf16(vf[c][ct], pa, acc[ct], 0, 0, 0);
    }
    __builtin_amdgcn_s_setprio(0);
  };

  const int nt = qt + 1;
  bf16x8 kfA[2][4], kfB[2][4];
  loadk(kfA, 0);
  int kt = 0;
  while (kt + 2 <= nt) {
    loadk(kfB, kt + 1);
    compute(kfA, kt);
    if (kt + 2 < nt) loadk(kfA, kt + 2);
    compute(kfB, kt + 1);
    kt += 2;
  }
  if (kt < nt) compute(kfA, kt);

  float inv = 1.f / lrun;
  bf16* orow = Ob + (size_t)(b * S_ + q) * D_ + h * HD_;
#pragma unroll
  for (int ct = 0; ct < 4; ++ct) {
    bf16x4 o = {(bf16)(acc[ct][0] * inv), (bf16)(acc[ct][1] * inv),
                (bf16)(acc[ct][2] * inv), (bf16)(acc[ct][3] * inv)};
    *(bf16x4*)&orow[ct * 16 + lg * 4] = o;
  }
}

// ---------------------------------------------------------------- launch
extern "C" void kernel_launch(void* const* d_in, const int* in_sizes, int n_in,
                              void* d_out, int out_size, void* d_ws,
                              size_t ws_size, hipStream_t stream) {
  const float* x  = (const float*)d_in[0];
  const float* Wq = (const float*)d_in[1];
  const float* bq = (const float*)d_in[2];
  const float* Wk = (const float*)d_in[3];
  const float* bk = (const float*)d_in[4];
  const float* Wv = (const float*)d_in[5];
  const float* bv = (const float*)d_in[6];
  const float* Wo = (const float*)d_in[7];
  const float* bo = (const float*)d_in[8];
  float* out = (float*)d_out;

  char* ws = (char*)d_ws;
  bf16* xb  = (bf16*)(ws);                    // 8 MB: x bf16 [4096][1024]
  bf16* wt  = (bf16*)(ws + (8u << 20));       // 8 MB: Wq^T|Wk^T|Wv^T|Wo^T bf16
  bf16* qb  = (bf16*)(ws + (16u << 20));      // 8 MB
  bf16* kb  = (bf16*)(ws + (24u << 20));      // 8 MB
  bf16* vtb = (bf16*)(ws + (32u << 20));      // 8 MB  [B][H][HD][S]
  bf16* atb = (bf16*)(ws + (40u << 20));      // 8 MB  attention out bf16

  const int M = B_ * S_;  // 4096

  cast_f32_bf16<<<dim3((M * D_) / 1024), 256, 0, stream>>>(x, xb, (M * D_) / 4);
  wtrans<<<dim3(32, 32, 4), dim3(32, 8), 0, stream>>>(Wq, Wk, Wv, Wo, wt);

  gemm_qkv<<<dim3(24, 32), 256, 0, stream>>>(xb, wt, bq, bk, bv, qb, kb, vtb);

  attn_nb<<<dim3(32, 32), 256, 0, stream>>>(qb, kb, vtb, atb);

  gemm128<<<dim3(8, 32), 256, 0, stream>>>(atb, wt + (3u << 20), bo, out, M, D_, D_);
}

// Round 5
// 170.051 us; speedup vs baseline: 1.7330x; 1.3650x over previous
//
#include <hip/hip_runtime.h>
#include <hip/hip_bf16.h>
#include <stdint.h>

typedef __bf16 bf16;
typedef __bf16 bf16x8 __attribute__((ext_vector_type(8)));
typedef __bf16 bf16x4 __attribute__((ext_vector_type(4)));
typedef float f32x4 __attribute__((ext_vector_type(4)));

#define B_  2
#define S_  2048
#define D_  1024
#define H_  16
#define HD_ 64

typedef __attribute__((address_space(1))) uint32_t gu32;
typedef __attribute__((address_space(3))) uint32_t lu32;

__device__ __forceinline__ void gload16(void* lds, const void* g) {
  __builtin_amdgcn_global_load_lds((const gu32*)(uintptr_t)g,
                                   (lu32*)(uint32_t)(uintptr_t)lds,
                                   16, 0, 0);
}

// ---------------------------------------------------------------- cast x
__global__ __launch_bounds__(256) void cast_f32_bf16(
    const float* __restrict__ in, bf16* __restrict__ out, int n4) {
  int i = blockIdx.x * 256 + threadIdx.x;
  if (i < n4) {
    float4 v = ((const float4*)in)[i];
    bf16x4 o = {(bf16)v.x, (bf16)v.y, (bf16)v.z, (bf16)v.w};
    ((bf16x4*)out)[i] = o;
  }
}

// ------------------------------------------------- transpose-cast weights
__global__ __launch_bounds__(256) void wtrans(
    const float* __restrict__ w0, const float* __restrict__ w1,
    const float* __restrict__ w2, const float* __restrict__ w3,
    bf16* __restrict__ out) {
  int z = blockIdx.z;
  const float* src = (z == 0) ? w0 : (z == 1) ? w1 : (z == 2) ? w2 : w3;
  bf16* dst = out + ((size_t)z << 20);
  __shared__ float tile[32][33];
  int tx = threadIdx.x, ty = threadIdx.y;
  int x0 = blockIdx.x * 32, y0 = blockIdx.y * 32;
#pragma unroll
  for (int r = 0; r < 4; ++r)
    tile[ty + r * 8][tx] = src[(size_t)(y0 + ty + r * 8) * D_ + x0 + tx];
  __syncthreads();
#pragma unroll
  for (int r = 0; r < 4; ++r)
    dst[(size_t)(x0 + ty + r * 8) * D_ + y0 + tx] = (bf16)tile[tx][ty + r * 8];
}

// ------------------------------------------------- fused QKV projection
__global__ __launch_bounds__(256) void gemm_qkv(
    const bf16* __restrict__ A, const bf16* __restrict__ Bt,
    const float* __restrict__ bq, const float* __restrict__ bk,
    const float* __restrict__ bv,
    bf16* __restrict__ qb, bf16* __restrict__ kb, bf16* __restrict__ vtb) {
  __shared__ bf16 As[128 * 64];
  __shared__ bf16 Bs[128 * 64];
  const int K = D_;
  int tid = threadIdx.x;
  int lane = tid & 63, wid = tid >> 6;
  int ln15 = lane & 15, lg = lane >> 4;
  int wr = wid >> 1, wc = wid & 1;
  int m0 = blockIdx.y * 128, n0g = blockIdx.x * 128;

  f32x4 acc[4][4] = {};

  for (int k0 = 0; k0 < K; k0 += 64) {
#pragma unroll
    for (int i = 0; i < 4; ++i) {
      int idx = (i * 256 + tid) * 8;
      int r = idx >> 6, c = idx & 63;
      gload16(&As[(size_t)(i * 256 + wid * 64) * 8],
              A + (size_t)(m0 + r) * K + k0 + c);
      gload16(&Bs[(size_t)(i * 256 + wid * 64) * 8],
              Bt + (size_t)(n0g + r) * K + k0 + c);
    }
    __syncthreads();
#pragma unroll
    for (int kk = 0; kk < 64; kk += 32) {
      bf16x8 af[4], bfr[4];
#pragma unroll
      for (int t = 0; t < 4; ++t)
        af[t] = *(const bf16x8*)&As[(wr * 64 + t * 16 + ln15) * 64 + kk + lg * 8];
#pragma unroll
      for (int t = 0; t < 4; ++t)
        bfr[t] = *(const bf16x8*)&Bs[(wc * 64 + t * 16 + ln15) * 64 + kk + lg * 8];
#pragma unroll
      for (int mi = 0; mi < 4; ++mi)
#pragma unroll
        for (int ni = 0; ni < 4; ++ni)
          acc[mi][ni] = __builtin_amdgcn_mfma_f32_16x16x32_bf16(
              af[mi], bfr[ni], acc[mi][ni], 0, 0, 0);
    }
    __syncthreads();
  }

  int seg = n0g >> 10;  // block-uniform (128 | 1024)
  const float* bias = (seg == 0) ? bq : (seg == 1) ? bk : bv;
  int n0 = n0g & 1023;
#pragma unroll
  for (int ni = 0; ni < 4; ++ni) {
    int n = n0 + wc * 64 + ni * 16 + ln15;
    float bvl = bias[n];
#pragma unroll
    for (int mi = 0; mi < 4; ++mi) {
      int mb = m0 + wr * 64 + mi * 16 + lg * 4;
#pragma unroll
      for (int j = 0; j < 4; ++j) {
        int m = mb + j;
        float v = acc[mi][ni][j] + bvl;
        if (seg == 0) {
          qb[(size_t)m * D_ + n] = (bf16)v;
        } else if (seg == 1) {
          kb[(size_t)m * D_ + n] = (bf16)v;
        } else {
          int bb = m >> 11, s = m & 2047, hh = n >> 6, dd = n & 63;
          vtb[(((size_t)bb * H_ + hh) * HD_ + dd) * S_ + s] = (bf16)v;
        }
      }
    }
  }
}

// ---------------------------------------------------------------- GEMM (O-proj)
__global__ __launch_bounds__(256) void gemm128(
    const bf16* __restrict__ A, const bf16* __restrict__ Bt,
    const float* __restrict__ bias, float* __restrict__ outf,
    int M, int N, int K) {
  __shared__ bf16 As[128 * 64];
  __shared__ bf16 Bs[128 * 64];
  int tid = threadIdx.x;
  int lane = tid & 63, wid = tid >> 6;
  int ln15 = lane & 15, lg = lane >> 4;
  int wr = wid >> 1, wc = wid & 1;
  int m0 = blockIdx.y * 128, n0 = blockIdx.x * 128;

  f32x4 acc[4][4] = {};

  for (int k0 = 0; k0 < K; k0 += 64) {
#pragma unroll
    for (int i = 0; i < 4; ++i) {
      int idx = (i * 256 + tid) * 8;
      int r = idx >> 6, c = idx & 63;
      gload16(&As[(size_t)(i * 256 + wid * 64) * 8],
              A + (size_t)(m0 + r) * K + k0 + c);
      gload16(&Bs[(size_t)(i * 256 + wid * 64) * 8],
              Bt + (size_t)(n0 + r) * K + k0 + c);
    }
    __syncthreads();
#pragma unroll
    for (int kk = 0; kk < 64; kk += 32) {
      bf16x8 af[4], bfr[4];
#pragma unroll
      for (int t = 0; t < 4; ++t)
        af[t] = *(const bf16x8*)&As[(wr * 64 + t * 16 + ln15) * 64 + kk + lg * 8];
#pragma unroll
      for (int t = 0; t < 4; ++t)
        bfr[t] = *(const bf16x8*)&Bs[(wc * 64 + t * 16 + ln15) * 64 + kk + lg * 8];
#pragma unroll
      for (int mi = 0; mi < 4; ++mi)
#pragma unroll
        for (int ni = 0; ni < 4; ++ni)
          acc[mi][ni] = __builtin_amdgcn_mfma_f32_16x16x32_bf16(
              af[mi], bfr[ni], acc[mi][ni], 0, 0, 0);
    }
    __syncthreads();
  }

#pragma unroll
  for (int ni = 0; ni < 4; ++ni) {
    int n = n0 + wc * 64 + ni * 16 + ln15;
    float bvl = bias[n];
#pragma unroll
    for (int mi = 0; mi < 4; ++mi) {
      int mb = m0 + wr * 64 + mi * 16 + lg * 4;
#pragma unroll
      for (int j = 0; j < 4; ++j)
        outf[(size_t)(mb + j) * N + n] = acc[mi][ni][j] + bvl;
    }
  }
}

// ------------------------------------------------------------- attention
// Block-cooperative flash attention, 2-phase pipeline (T3 minimum form):
//  - block = 4 waves x 32 q-rows = 128 q-rows; grid (bh=32, qt=16)
//  - K-tile & V^T-tile (64x64 bf16) staged ONCE per block into LDS via
//    global_load_lds, double-buffered; stage(kt+1) issued before compute(kt);
//    one __syncthreads per tile.
//  - XOR swizzle (rule #21): linear LDS dest, inverse-swizzled global source,
//    swizzled ds_read -> 16-way bank conflict becomes 2-way (free).
//  - swapped QK^T (softmax lane-local), swapped PV via per-wave P-LDS slab.
__global__ __launch_bounds__(256) void attn_lds(
    const bf16* __restrict__ Q, const bf16* __restrict__ Kb,
    const bf16* __restrict__ Vt, bf16* __restrict__ Ob) {
  const float CEXP = 0.125f * 1.44269504088896f;  // scale * log2(e)
  __shared__ bf16 Ks[2][64 * 64];
  __shared__ bf16 Vs[2][64 * 64];
  __shared__ bf16 Pl[4][2][16 * 72];

  int bh = blockIdx.x;
  int qt = (int)(gridDim.y - 1) - (int)blockIdx.y;  // longest-first
  int b = bh >> 4, h = bh & 15;
  int tid = threadIdx.x, lane = tid & 63, w = tid >> 6;
  int ln15 = lane & 15, lg = lane >> 4;
  int qw = qt * 128 + w * 32;  // this wave's first q-row

  // Q fragments for both 16-row groups
  bf16x8 qf[2][2];
#pragma unroll
  for (int g = 0; g < 2; ++g) {
    const bf16* qptr =
        Q + (size_t)(b * S_ + qw + g * 16 + ln15) * D_ + h * HD_ + lg * 8;
    qf[g][0] = *(const bf16x8*)qptr;
    qf[g][1] = *(const bf16x8*)(qptr + 32);
  }

  const bf16* kbase = Kb + (size_t)(b * S_) * D_ + h * HD_;  // row stride D_
  const bf16* vbase = Vt + (size_t)bh * HD_ * S_;            // [d][s]

  f32x4 acc[2][4] = {};
  float mrun[2] = {-1e30f, -1e30f};
  float lrun[2] = {0.f, 0.f};

  // swizzled-source staging geometry: lane covers (row r0+rl, dest chunk l&7);
  // source chunk = (l&7) ^ rl so that LDS[r*128 + (c^(r&7))*16] = T[r][c*16B]
  int rl = lane >> 3;
  int schunk = (lane & 7) ^ rl;

  auto stage = [&](int buf, int kt) {
    int kk0 = kt * 64;
#pragma unroll
    for (int i = 0; i < 2; ++i) {
      int r0 = w * 16 + i * 8;
      gload16(&Ks[buf][r0 * 64],
              kbase + (size_t)(kk0 + r0 + rl) * D_ + schunk * 8);
      gload16(&Vs[buf][r0 * 64],
              vbase + (size_t)(r0 + rl) * S_ + kk0 + schunk * 8);
    }
  };

  const int nt = 2 * qt + 2;
  int cur = 0;
  stage(0, 0);
  __syncthreads();

  int r7 = ln15 & 7;
  for (int kt = 0; kt < nt; ++kt) {
    if (kt + 1 < nt) stage(cur ^ 1, kt + 1);
    int kk0 = kt * 64;

    // K fragments (swizzled read), then QK^T for both groups
    bf16x8 kf[2][4];
#pragma unroll
    for (int c = 0; c < 2; ++c)
#pragma unroll
      for (int ct = 0; ct < 4; ++ct)
        kf[c][ct] = *(const bf16x8*)&Ks[cur][(ct * 16 + ln15) * 64 +
                                            (((c * 4 + lg) ^ r7) * 8)];

    f32x4 sa[2][4] = {};
    __builtin_amdgcn_s_setprio(1);
#pragma unroll
    for (int c = 0; c < 2; ++c)
#pragma unroll
      for (int g = 0; g < 2; ++g)
#pragma unroll
        for (int ct = 0; ct < 4; ++ct)
          sa[g][ct] = __builtin_amdgcn_mfma_f32_16x16x32_bf16(
              kf[c][ct], qf[g][c], sa[g][ct], 0, 0, 0);
    __builtin_amdgcn_s_setprio(0);

    // V^T fragments issued now (consumed after softmax; kf regs retire)
    bf16x8 vf[2][4];
#pragma unroll
    for (int c = 0; c < 2; ++c)
#pragma unroll
      for (int ct = 0; ct < 4; ++ct)
        vf[c][ct] = *(const bf16x8*)&Vs[cur][(ct * 16 + ln15) * 64 +
                                            (((c * 4 + lg) ^ r7) * 8)];

#pragma unroll
    for (int g = 0; g < 2; ++g) {
      int qg0 = qw + g * 16;
      int q = qg0 + ln15;
      if (kk0 + 63 > qg0) {  // causal mask (wave-uniform branch)
#pragma unroll
        for (int ct = 0; ct < 4; ++ct) {
          int kb0 = kk0 + ct * 16 + lg * 4;
#pragma unroll
          for (int j = 0; j < 4; ++j)
            if (kb0 + j > q) sa[g][ct][j] = -1e9f;
        }
      }

      // lane-local softmax (16 scores/lane) + 2 shfl across lane-groups
      f32x4 mx = sa[g][0];
      mx = __builtin_elementwise_max(mx, sa[g][1]);
      mx = __builtin_elementwise_max(mx, sa[g][2]);
      mx = __builtin_elementwise_max(mx, sa[g][3]);
      float t = fmaxf(fmaxf(mx[0], mx[1]), fmaxf(mx[2], mx[3]));
      t = fmaxf(t, __shfl_xor(t, 16));
      t = fmaxf(t, __shfl_xor(t, 32));
      float mnew = fmaxf(mrun[g], t);
      float rs = exp2f((mrun[g] - mnew) * CEXP);

      float p[4][4];
      float ps = 0.f;
#pragma unroll
      for (int ct = 0; ct < 4; ++ct) {
#pragma unroll
        for (int j = 0; j < 4; ++j) {
          p[ct][j] = exp2f((sa[g][ct][j] - mnew) * CEXP);
          ps += p[ct][j];
        }
      }
      ps += __shfl_xor(ps, 16);
      ps += __shfl_xor(ps, 32);
      lrun[g] = lrun[g] * rs + ps;
      mrun[g] = mnew;
#pragma unroll
      for (int ct = 0; ct < 4; ++ct)
#pragma unroll
        for (int j = 0; j < 4; ++j) acc[g][ct][j] *= rs;

      // P -> per-wave LDS slab (stride 72), packed 8B writes
      bf16* pw = &Pl[w][g][0];
#pragma unroll
      for (int ct = 0; ct < 4; ++ct) {
        bf16x4 pk = {(bf16)p[ct][0], (bf16)p[ct][1],
                     (bf16)p[ct][2], (bf16)p[ct][3]};
        *(bf16x4*)&pw[ln15 * 72 + ct * 16 + lg * 4] = pk;
      }

      // PV (swapped): acc += V^T x P
      __builtin_amdgcn_s_setprio(1);
#pragma unroll
      for (int c = 0; c < 2; ++c) {
        bf16x8 pa = *(const bf16x8*)&pw[ln15 * 72 + c * 32 + lg * 8];
#pragma unroll
        for (int ct = 0; ct < 4; ++ct)
          acc[g][ct] = __builtin_amdgcn_mfma_f32_16x16x32_bf16(
              vf[c][ct], pa, acc[g][ct], 0, 0, 0);
      }
      __builtin_amdgcn_s_setprio(0);
    }

    __syncthreads();
    cur ^= 1;
  }

#pragma unroll
  for (int g = 0; g < 2; ++g) {
    float inv = 1.f / lrun[g];
    int q = qw + g * 16 + ln15;
    bf16* orow = Ob + (size_t)(b * S_ + q) * D_ + h * HD_;
#pragma unroll
    for (int ct = 0; ct < 4; ++ct) {
      bf16x4 o = {(bf16)(acc[g][ct][0] * inv), (bf16)(acc[g][ct][1] * inv),
                  (bf16)(acc[g][ct][2] * inv), (bf16)(acc[g][ct][3] * inv)};
      *(bf16x4*)&orow[ct * 16 + lg * 4] = o;
    }
  }
}

// ---------------------------------------------------------------- launch
extern "C" void kernel_launch(void* const* d_in, const int* in_sizes, int n_in,
                              void* d_out, int out_size, void* d_ws,
                              size_t ws_size, hipStream_t stream) {
  const float* x  = (const float*)d_in[0];
  const float* Wq = (const float*)d_in[1];
  const float* bq = (const float*)d_in[2];
  const float* Wk = (const float*)d_in[3];
  const float* bk = (const float*)d_in[4];
  const float* Wv = (const float*)d_in[5];
  const float* bv = (const float*)d_in[6];
  const float* Wo = (const float*)d_in[7];
  const float* bo = (const float*)d_in[8];
  float* out = (float*)d_out;

  char* ws = (char*)d_ws;
  bf16* xb  = (bf16*)(ws);                    // 8 MB: x bf16 [4096][1024]
  bf16* wt  = (bf16*)(ws + (8u << 20));       // 8 MB: Wq^T|Wk^T|Wv^T|Wo^T bf16
  bf16* qb  = (bf16*)(ws + (16u << 20));      // 8 MB
  bf16* kb  = (bf16*)(ws + (24u << 20));      // 8 MB
  bf16* vtb = (bf16*)(ws + (32u << 20));      // 8 MB  [B][H][HD][S]
  bf16* atb = (bf16*)(ws + (40u << 20));      // 8 MB  attention out bf16

  const int M = B_ * S_;  // 4096

  cast_f32_bf16<<<dim3((M * D_) / 1024), 256, 0, stream>>>(x, xb, (M * D_) / 4);
  wtrans<<<dim3(32, 32, 4), dim3(32, 8), 0, stream>>>(Wq, Wk, Wv, Wo, wt);

  gemm_qkv<<<dim3(24, 32), 256, 0, stream>>>(xb, wt, bq, bk, bv, qb, kb, vtb);

  attn_lds<<<dim3(32, 16), 256, 0, stream>>>(qb, kb, vtb, atb);

  gemm128<<<dim3(8, 32), 256, 0, stream>>>(atb, wt + (3u << 20), bo, out, M, D_, D_);
}

// Round 6
// 158.804 us; speedup vs baseline: 1.8557x; 1.0708x over previous
//
#include <hip/hip_runtime.h>
#include <hip/hip_bf16.h>
#include <stdint.h>

typedef __bf16 bf16;
typedef __bf16 bf16x8 __attribute__((ext_vector_type(8)));
typedef __bf16 bf16x4 __attribute__((ext_vector_type(4)));
typedef float f32x4 __attribute__((ext_vector_type(4)));

#define B_  2
#define S_  2048
#define D_  1024
#define H_  16
#define HD_ 64

typedef __attribute__((address_space(1))) uint32_t gu32;
typedef __attribute__((address_space(3))) uint32_t lu32;

__device__ __forceinline__ void gload16(void* lds, const void* g) {
  __builtin_amdgcn_global_load_lds((const gu32*)(uintptr_t)g,
                                   (lu32*)(uint32_t)(uintptr_t)lds,
                                   16, 0, 0);
}

// ---------------------------------------------------------------- cast x
__global__ __launch_bounds__(256) void cast_f32_bf16(
    const float* __restrict__ in, bf16* __restrict__ out, int n4) {
  int i = blockIdx.x * 256 + threadIdx.x;
  if (i < n4) {
    float4 v = ((const float4*)in)[i];
    bf16x4 o = {(bf16)v.x, (bf16)v.y, (bf16)v.z, (bf16)v.w};
    ((bf16x4*)out)[i] = o;
  }
}

// ------------------------------------------------- transpose-cast weights
__global__ __launch_bounds__(256) void wtrans(
    const float* __restrict__ w0, const float* __restrict__ w1,
    const float* __restrict__ w2, const float* __restrict__ w3,
    bf16* __restrict__ out) {
  int z = blockIdx.z;
  const float* src = (z == 0) ? w0 : (z == 1) ? w1 : (z == 2) ? w2 : w3;
  bf16* dst = out + ((size_t)z << 20);
  __shared__ float tile[32][33];
  int tx = threadIdx.x, ty = threadIdx.y;
  int x0 = blockIdx.x * 32, y0 = blockIdx.y * 32;
#pragma unroll
  for (int r = 0; r < 4; ++r)
    tile[ty + r * 8][tx] = src[(size_t)(y0 + ty + r * 8) * D_ + x0 + tx];
  __syncthreads();
#pragma unroll
  for (int r = 0; r < 4; ++r)
    dst[(size_t)(x0 + ty + r * 8) * D_ + y0 + tx] = (bf16)tile[tx][ty + r * 8];
}

// ------------------------------------------------- fused QKV projection
// seg 0 -> qb, seg 1 -> kb, seg 2 -> V^T via LDS transpose (s-contiguous)
__global__ __launch_bounds__(256) void gemm_qkv(
    const bf16* __restrict__ A, const bf16* __restrict__ Bt,
    const float* __restrict__ bq, const float* __restrict__ bk,
    const float* __restrict__ bv,
    bf16* __restrict__ qb, bf16* __restrict__ kb, bf16* __restrict__ vtb) {
  __shared__ __align__(16) bf16 smem[128 * 136];  // As|Bs staging + V^T transpose
  bf16* As = smem;
  bf16* Bs = smem + 128 * 64;
  const int K = D_;
  int tid = threadIdx.x;
  int lane = tid & 63, wid = tid >> 6;
  int ln15 = lane & 15, lg = lane >> 4;
  int wr = wid >> 1, wc = wid & 1;
  int m0 = blockIdx.y * 128, n0g = blockIdx.x * 128;

  f32x4 acc[4][4] = {};

  for (int k0 = 0; k0 < K; k0 += 64) {
#pragma unroll
    for (int i = 0; i < 4; ++i) {
      int idx = (i * 256 + tid) * 8;
      int r = idx >> 6, c = idx & 63;
      gload16(&As[(size_t)(i * 256 + wid * 64) * 8],
              A + (size_t)(m0 + r) * K + k0 + c);
      gload16(&Bs[(size_t)(i * 256 + wid * 64) * 8],
              Bt + (size_t)(n0g + r) * K + k0 + c);
    }
    __syncthreads();
#pragma unroll
    for (int kk = 0; kk < 64; kk += 32) {
      bf16x8 af[4], bfr[4];
#pragma unroll
      for (int t = 0; t < 4; ++t)
        af[t] = *(const bf16x8*)&As[(wr * 64 + t * 16 + ln15) * 64 + kk + lg * 8];
#pragma unroll
      for (int t = 0; t < 4; ++t)
        bfr[t] = *(const bf16x8*)&Bs[(wc * 64 + t * 16 + ln15) * 64 + kk + lg * 8];
#pragma unroll
      for (int mi = 0; mi < 4; ++mi)
#pragma unroll
        for (int ni = 0; ni < 4; ++ni)
          acc[mi][ni] = __builtin_amdgcn_mfma_f32_16x16x32_bf16(
              af[mi], bfr[ni], acc[mi][ni], 0, 0, 0);
    }
    __syncthreads();
  }

  int seg = n0g >> 10;  // block-uniform (128 | 1024)
  int n0 = n0g & 1023;

  if (seg == 2) {
    // V^T epilogue: acc -> LDS [n_local][m_local] (stride 136, 2-way free),
    // then s-contiguous bf16x8 global writes.
    bf16 (*tr)[136] = (bf16(*)[136])smem;
#pragma unroll
    for (int ni = 0; ni < 4; ++ni) {
      int nl = wc * 64 + ni * 16 + ln15;
      float bvl = bv[n0 + nl];
#pragma unroll
      for (int mi = 0; mi < 4; ++mi) {
        int ml = wr * 64 + mi * 16 + lg * 4;
        bf16x4 pk = {(bf16)(acc[mi][ni][0] + bvl), (bf16)(acc[mi][ni][1] + bvl),
                     (bf16)(acc[mi][ni][2] + bvl), (bf16)(acc[mi][ni][3] + bvl)};
        *(bf16x4*)&tr[nl][ml] = pk;
      }
    }
    __syncthreads();
    int r = tid >> 1, hf = tid & 1;  // r = n_local, hf selects 64-wide s half
    int n = n0 + r;
    int hh = n >> 6, dd = n & 63;
    int bb = m0 >> 11, s0c = (m0 & 2047) + hf * 64;
    bf16* dst = vtb + (((size_t)bb * H_ + hh) * HD_ + dd) * S_ + s0c;
    const bf16* srcr = &tr[r][hf * 64];
#pragma unroll
    for (int k = 0; k < 8; ++k)
      *(bf16x8*)&dst[k * 8] = *(const bf16x8*)&srcr[k * 8];
  } else {
    const float* bias = (seg == 0) ? bq : bk;
    bf16* outp = (seg == 0) ? qb : kb;
#pragma unroll
    for (int ni = 0; ni < 4; ++ni) {
      int n = n0 + wc * 64 + ni * 16 + ln15;
      float bvl = bias[n];
#pragma unroll
      for (int mi = 0; mi < 4; ++mi) {
        int mb = m0 + wr * 64 + mi * 16 + lg * 4;
#pragma unroll
        for (int j = 0; j < 4; ++j)
          outp[(size_t)(mb + j) * D_ + n] = (bf16)(acc[mi][ni][j] + bvl);
      }
    }
  }
}

// ---------------------------------------------------------------- GEMM (O-proj)
__global__ __launch_bounds__(256) void gemm128(
    const bf16* __restrict__ A, const bf16* __restrict__ Bt,
    const float* __restrict__ bias, float* __restrict__ outf,
    int M, int N, int K) {
  __shared__ bf16 As[128 * 64];
  __shared__ bf16 Bs[128 * 64];
  int tid = threadIdx.x;
  int lane = tid & 63, wid = tid >> 6;
  int ln15 = lane & 15, lg = lane >> 4;
  int wr = wid >> 1, wc = wid & 1;
  int m0 = blockIdx.y * 128, n0 = blockIdx.x * 128;

  f32x4 acc[4][4] = {};

  for (int k0 = 0; k0 < K; k0 += 64) {
#pragma unroll
    for (int i = 0; i < 4; ++i) {
      int idx = (i * 256 + tid) * 8;
      int r = idx >> 6, c = idx & 63;
      gload16(&As[(size_t)(i * 256 + wid * 64) * 8],
              A + (size_t)(m0 + r) * K + k0 + c);
      gload16(&Bs[(size_t)(i * 256 + wid * 64) * 8],
              Bt + (size_t)(n0 + r) * K + k0 + c);
    }
    __syncthreads();
#pragma unroll
    for (int kk = 0; kk < 64; kk += 32) {
      bf16x8 af[4], bfr[4];
#pragma unroll
      for (int t = 0; t < 4; ++t)
        af[t] = *(const bf16x8*)&As[(wr * 64 + t * 16 + ln15) * 64 + kk + lg * 8];
#pragma unroll
      for (int t = 0; t < 4; ++t)
        bfr[t] = *(const bf16x8*)&Bs[(wc * 64 + t * 16 + ln15) * 64 + kk + lg * 8];
#pragma unroll
      for (int mi = 0; mi < 4; ++mi)
#pragma unroll
        for (int ni = 0; ni < 4; ++ni)
          acc[mi][ni] = __builtin_amdgcn_mfma_f32_16x16x32_bf16(
              af[mi], bfr[ni], acc[mi][ni], 0, 0, 0);
    }
    __syncthreads();
  }

#pragma unroll
  for (int ni = 0; ni < 4; ++ni) {
    int n = n0 + wc * 64 + ni * 16 + ln15;
    float bvl = bias[n];
#pragma unroll
    for (int mi = 0; mi < 4; ++mi) {
      int mb = m0 + wr * 64 + mi * 16 + lg * 4;
#pragma unroll
      for (int j = 0; j < 4; ++j)
        outf[(size_t)(mb + j) * N + n] = acc[mi][ni][j] + bvl;
    }
  }
}

// ------------------------------------------------------------- attention
// Block-cooperative flash attention, 2-phase pipeline, balanced grid:
// y<8 -> heavy tiles qt=15..8 (descending), y>=8 -> light qt=0..7
// (ascending) so each CU's two resident blocks sum to 34 tile-units.
__global__ __launch_bounds__(256) void attn_lds(
    const bf16* __restrict__ Q, const bf16* __restrict__ Kb,
    const bf16* __restrict__ Vt, bf16* __restrict__ Ob) {
  const float CEXP = 0.125f * 1.44269504088896f;  // scale * log2(e)
  __shared__ bf16 Ks[2][64 * 64];
  __shared__ bf16 Vs[2][64 * 64];
  __shared__ bf16 Pl[4][2][16 * 72];

  int bh = blockIdx.x;
  int y = blockIdx.y;
  int qt = (y < 8) ? (15 - y) : (y - 8);  // balanced heavy/light pairing
  int b = bh >> 4, h = bh & 15;
  int tid = threadIdx.x, lane = tid & 63, w = tid >> 6;
  int ln15 = lane & 15, lg = lane >> 4;
  int qw = qt * 128 + w * 32;  // this wave's first q-row

  // Q fragments for both 16-row groups
  bf16x8 qf[2][2];
#pragma unroll
  for (int g = 0; g < 2; ++g) {
    const bf16* qptr =
        Q + (size_t)(b * S_ + qw + g * 16 + ln15) * D_ + h * HD_ + lg * 8;
    qf[g][0] = *(const bf16x8*)qptr;
    qf[g][1] = *(const bf16x8*)(qptr + 32);
  }

  const bf16* kbase = Kb + (size_t)(b * S_) * D_ + h * HD_;  // row stride D_
  const bf16* vbase = Vt + (size_t)bh * HD_ * S_;            // [d][s]

  f32x4 acc[2][4] = {};
  float mrun[2] = {-1e30f, -1e30f};
  float lrun[2] = {0.f, 0.f};

  // swizzled-source staging: LDS[r*128B + (c^(r&7))*16B] = T[r][c*16B]
  int rl = lane >> 3;
  int schunk = (lane & 7) ^ rl;

  auto stage = [&](int buf, int kt) {
    int kk0 = kt * 64;
#pragma unroll
    for (int i = 0; i < 2; ++i) {
      int r0 = w * 16 + i * 8;
      gload16(&Ks[buf][r0 * 64],
              kbase + (size_t)(kk0 + r0 + rl) * D_ + schunk * 8);
      gload16(&Vs[buf][r0 * 64],
              vbase + (size_t)(r0 + rl) * S_ + kk0 + schunk * 8);
    }
  };

  const int nt = 2 * qt + 2;
  int cur = 0;
  stage(0, 0);
  __syncthreads();

  int r7 = ln15 & 7;
  for (int kt = 0; kt < nt; ++kt) {
    if (kt + 1 < nt) stage(cur ^ 1, kt + 1);
    int kk0 = kt * 64;

    bf16x8 kf[2][4];
#pragma unroll
    for (int c = 0; c < 2; ++c)
#pragma unroll
      for (int ct = 0; ct < 4; ++ct)
        kf[c][ct] = *(const bf16x8*)&Ks[cur][(ct * 16 + ln15) * 64 +
                                            (((c * 4 + lg) ^ r7) * 8)];

    f32x4 sa[2][4] = {};
    __builtin_amdgcn_s_setprio(1);
#pragma unroll
    for (int c = 0; c < 2; ++c)
#pragma unroll
      for (int g = 0; g < 2; ++g)
#pragma unroll
        for (int ct = 0; ct < 4; ++ct)
          sa[g][ct] = __builtin_amdgcn_mfma_f32_16x16x32_bf16(
              kf[c][ct], qf[g][c], sa[g][ct], 0, 0, 0);
    __builtin_amdgcn_s_setprio(0);

    bf16x8 vf[2][4];
#pragma unroll
    for (int c = 0; c < 2; ++c)
#pragma unroll
      for (int ct = 0; ct < 4; ++ct)
        vf[c][ct] = *(const bf16x8*)&Vs[cur][(ct * 16 + ln15) * 64 +
                                            (((c * 4 + lg) ^ r7) * 8)];

#pragma unroll
    for (int g = 0; g < 2; ++g) {
      int qg0 = qw + g * 16;
      int q = qg0 + ln15;
      if (kk0 + 63 > qg0) {  // causal mask (wave-uniform branch)
#pragma unroll
        for (int ct = 0; ct < 4; ++ct) {
          int kb0 = kk0 + ct * 16 + lg * 4;
#pragma unroll
          for (int j = 0; j < 4; ++j)
            if (kb0 + j > q) sa[g][ct][j] = -1e9f;
        }
      }

      // lane-local softmax (16 scores/lane) + 2 shfl across lane-groups
      f32x4 mx = sa[g][0];
      mx = __builtin_elementwise_max(mx, sa[g][1]);
      mx = __builtin_elementwise_max(mx, sa[g][2]);
      mx = __builtin_elementwise_max(mx, sa[g][3]);
      float t = fmaxf(fmaxf(mx[0], mx[1]), fmaxf(mx[2], mx[3]));
      t = fmaxf(t, __shfl_xor(t, 16));
      t = fmaxf(t, __shfl_xor(t, 32));
      float mnew = fmaxf(mrun[g], t);
      float rs = exp2f((mrun[g] - mnew) * CEXP);

      float p[4][4];
      float ps = 0.f;
#pragma unroll
      for (int ct = 0; ct < 4; ++ct) {
#pragma unroll
        for (int j = 0; j < 4; ++j) {
          p[ct][j] = exp2f((sa[g][ct][j] - mnew) * CEXP);
          ps += p[ct][j];
        }
      }
      ps += __shfl_xor(ps, 16);
      ps += __shfl_xor(ps, 32);
      lrun[g] = lrun[g] * rs + ps;
      mrun[g] = mnew;
#pragma unroll
      for (int ct = 0; ct < 4; ++ct)
#pragma unroll
        for (int j = 0; j < 4; ++j) acc[g][ct][j] *= rs;

      bf16* pw = &Pl[w][g][0];
#pragma unroll
      for (int ct = 0; ct < 4; ++ct) {
        bf16x4 pk = {(bf16)p[ct][0], (bf16)p[ct][1],
                     (bf16)p[ct][2], (bf16)p[ct][3]};
        *(bf16x4*)&pw[ln15 * 72 + ct * 16 + lg * 4] = pk;
      }

      __builtin_amdgcn_s_setprio(1);
#pragma unroll
      for (int c = 0; c < 2; ++c) {
        bf16x8 pa = *(const bf16x8*)&pw[ln15 * 72 + c * 32 + lg * 8];
#pragma unroll
        for (int ct = 0; ct < 4; ++ct)
          acc[g][ct] = __builtin_amdgcn_mfma_f32_16x16x32_bf16(
              vf[c][ct], pa, acc[g][ct], 0, 0, 0);
      }
      __builtin_amdgcn_s_setprio(0);
    }

    __syncthreads();
    cur ^= 1;
  }

#pragma unroll
  for (int g = 0; g < 2; ++g) {
    float inv = 1.f / lrun[g];
    int q = qw + g * 16 + ln15;
    bf16* orow = Ob + (size_t)(b * S_ + q) * D_ + h * HD_;
#pragma unroll
    for (int ct = 0; ct < 4; ++ct) {
      bf16x4 o = {(bf16)(acc[g][ct][0] * inv), (bf16)(acc[g][ct][1] * inv),
                  (bf16)(acc[g][ct][2] * inv), (bf16)(acc[g][ct][3] * inv)};
      *(bf16x4*)&orow[ct * 16 + lg * 4] = o;
    }
  }
}

// ---------------------------------------------------------------- launch
extern "C" void kernel_launch(void* const* d_in, const int* in_sizes, int n_in,
                              void* d_out, int out_size, void* d_ws,
                              size_t ws_size, hipStream_t stream) {
  const float* x  = (const float*)d_in[0];
  const float* Wq = (const float*)d_in[1];
  const float* bq = (const float*)d_in[2];
  const float* Wk = (const float*)d_in[3];
  const float* bk = (const float*)d_in[4];
  const float* Wv = (const float*)d_in[5];
  const float* bv = (const float*)d_in[6];
  const float* Wo = (const float*)d_in[7];
  const float* bo = (const float*)d_in[8];
  float* out = (float*)d_out;

  char* ws = (char*)d_ws;
  bf16* xb  = (bf16*)(ws);                    // 8 MB: x bf16 [4096][1024]
  bf16* wt  = (bf16*)(ws + (8u << 20));       // 8 MB: Wq^T|Wk^T|Wv^T|Wo^T bf16
  bf16* qb  = (bf16*)(ws + (16u << 20));      // 8 MB
  bf16* kb  = (bf16*)(ws + (24u << 20));      // 8 MB
  bf16* vtb = (bf16*)(ws + (32u << 20));      // 8 MB  [B][H][HD][S]
  bf16* atb = (bf16*)(ws + (40u << 20));      // 8 MB  attention out bf16

  const int M = B_ * S_;  // 4096

  cast_f32_bf16<<<dim3((M * D_) / 1024), 256, 0, stream>>>(x, xb, (M * D_) / 4);
  wtrans<<<dim3(32, 32, 4), dim3(32, 8), 0, stream>>>(Wq, Wk, Wv, Wo, wt);

  gemm_qkv<<<dim3(24, 32), 256, 0, stream>>>(xb, wt, bq, bk, bv, qb, kb, vtb);

  attn_lds<<<dim3(32, 16), 256, 0, stream>>>(qb, kb, vtb, atb);

  gemm128<<<dim3(8, 32), 256, 0, stream>>>(atb, wt + (3u << 20), bo, out, M, D_, D_);
}